// Round 1
// baseline (832.388 us; speedup 1.0000x reference)
//
#include <hip/hip_runtime.h>
#include <stdint.h>

#define EMBED 256
#define HEADS 8
#define LEVELS 4
#define POINTS 4
#define HEAD_DIM 32
#define BS 2
#define LV_TOTAL 13294
#define LQ LV_TOTAL
#define TP 128 /* HEADS*LEVELS*POINTS */

#define VP_ROWS 16
#define QPB 8

// ---------------------------------------------------------------------------
// Kernel 1: v = value @ W_val + b_val, masked.  Output layout (b, lv, 256).
// One block = 16 rows; thread j owns output column j; A rows broadcast via LDS.
// ---------------------------------------------------------------------------
__global__ __launch_bounds__(256) void value_proj_kernel(
    const float* __restrict__ value, const uint8_t* __restrict__ mask,
    const float* __restrict__ W_val, const float* __restrict__ b_val,
    float* __restrict__ v_out, int n_rows) {
  __shared__ float a_s[VP_ROWS][EMBED];
  const int row0 = blockIdx.x * VP_ROWS;
  const int tid = threadIdx.x;

  for (int r = 0; r < VP_ROWS; ++r) {
    int row = row0 + r;
    a_s[r][tid] = (row < n_rows) ? value[(size_t)row * EMBED + tid] : 0.f;
  }
  __syncthreads();

  float acc[VP_ROWS];
#pragma unroll
  for (int r = 0; r < VP_ROWS; ++r) acc[r] = 0.f;

  for (int k = 0; k < EMBED; ++k) {
    float w = W_val[(size_t)k * EMBED + tid];
#pragma unroll
    for (int r = 0; r < VP_ROWS; ++r) acc[r] += a_s[r][k] * w;
  }

  const float bias = b_val[tid];
  for (int r = 0; r < VP_ROWS; ++r) {
    int row = row0 + r;
    if (row < n_rows) {
      float o = acc[r] + bias;
      if (mask[row]) o = 0.f;
      v_out[(size_t)row * EMBED + tid] = o;
    }
  }
}

// ---------------------------------------------------------------------------
// Kernel 2: fused offsets/attn/softmax/bilinear-sampling/output projection.
// One block handles QPB queries of one batch. 256 threads.
// ---------------------------------------------------------------------------
__global__ __launch_bounds__(256) void msda_kernel(
    const float* __restrict__ query, const float* __restrict__ refpts,
    const float* __restrict__ v,  // (BS, LV, 256) projected value
    const float* __restrict__ W_off, const float* __restrict__ b_off,
    const float* __restrict__ W_attn, const float* __restrict__ b_attn,
    const float* __restrict__ W_out, const float* __restrict__ b_out,
    float* __restrict__ out) {
  __shared__ float q_s[QPB][EMBED];
  __shared__ float off_s[QPB][EMBED];
  __shared__ float attn_s[QPB][TP];
  __shared__ float ref_s[QPB][LEVELS][2];
  __shared__ float o_s[QPB][EMBED];

  const int b = blockIdx.y;
  const int q0 = blockIdx.x * QPB;
  const int tid = threadIdx.x;

  // ---- stage query rows + reference points ----
  for (int r = 0; r < QPB; ++r) {
    int q = q0 + r;
    q_s[r][tid] = (q < LQ) ? query[((size_t)b * LQ + q) * EMBED + tid] : 0.f;
  }
  if (tid < QPB * LEVELS * 2) {
    int r = tid / (LEVELS * 2);
    int rem = tid % (LEVELS * 2);
    int q = q0 + r;
    ref_s[r][rem / 2][rem % 2] =
        (q < LQ) ? refpts[((size_t)b * LQ + q) * (LEVELS * 2) + rem] : 0.f;
  }
  __syncthreads();

  // ---- sampling offsets: off = q @ W_off + b_off  (256 cols) ----
  {
    float acc[QPB];
#pragma unroll
    for (int r = 0; r < QPB; ++r) acc[r] = 0.f;
    for (int k = 0; k < EMBED; ++k) {
      float w = W_off[(size_t)k * (TP * 2) + tid];
#pragma unroll
      for (int r = 0; r < QPB; ++r) acc[r] += q_s[r][k] * w;
    }
    float bo = b_off[tid];
#pragma unroll
    for (int r = 0; r < QPB; ++r) off_s[r][tid] = acc[r] + bo;
  }

  // ---- attention logits: q @ W_attn + b_attn  (128 cols) ----
  if (tid < TP) {
    float acc[QPB];
#pragma unroll
    for (int r = 0; r < QPB; ++r) acc[r] = 0.f;
    for (int k = 0; k < EMBED; ++k) {
      float w = W_attn[(size_t)k * TP + tid];
#pragma unroll
      for (int r = 0; r < QPB; ++r) acc[r] += q_s[r][k] * w;
    }
    float ba = b_attn[tid];
#pragma unroll
    for (int r = 0; r < QPB; ++r) attn_s[r][tid] = acc[r] + ba;
  }
  __syncthreads();

  // ---- softmax over 16 per (query, head) ----
  if (tid < QPB * HEADS) {
    int r = tid / HEADS, h = tid % HEADS;
    float* a = &attn_s[r][h * 16];
    float m = a[0];
#pragma unroll
    for (int i = 1; i < 16; ++i) m = fmaxf(m, a[i]);
    float e[16];
    float s = 0.f;
#pragma unroll
    for (int i = 0; i < 16; ++i) {
      e[i] = expf(a[i] - m);
      s += e[i];
    }
    float inv = 1.f / s;
#pragma unroll
    for (int i = 0; i < 16; ++i) a[i] = e[i] * inv;
  }
  __syncthreads();

  // ---- bilinear sampling: thread = (head h, dim d) ----
  const int h = tid >> 5;  // 0..7
  const int d = tid & 31;  // 0..31
  const int Hs[4] = {100, 50, 25, 13};
  const int Ws_[4] = {100, 50, 25, 13};
  const int Ls[4] = {0, 10000, 12500, 13125};

  for (int r = 0; r < QPB; ++r) {
    float acc = 0.f;
#pragma unroll
    for (int l = 0; l < LEVELS; ++l) {
      const int H = Hs[l], W = Ws_[l];
      const float fW = (float)W, fH = (float)H;
      const float rx = ref_s[r][l][0], ry = ref_s[r][l][1];
      const float* vlev = v + ((size_t)b * LV_TOTAL + Ls[l]) * EMBED;
#pragma unroll
      for (int p = 0; p < POINTS; ++p) {
        float ox = off_s[r][h * 32 + l * 8 + p * 2 + 0];
        float oy = off_s[r][h * 32 + l * 8 + p * 2 + 1];
        float aw = attn_s[r][h * 16 + l * 4 + p];
        float x = (rx + ox / fW) * fW - 0.5f;
        float y = (ry + oy / fH) * fH - 0.5f;
        float x0f = floorf(x), y0f = floorf(y);
        float lw = x - x0f, lh = y - y0f;
        int x0 = (int)x0f, y0 = (int)y0f;
#pragma unroll
        for (int c = 0; c < 4; ++c) {
          int dy = c >> 1, dx = c & 1;
          int xi = x0 + dx, yi = y0 + dy;
          bool valid = (xi >= 0) && (xi < W) && (yi >= 0) && (yi < H);
          float wc = (dy ? lh : 1.f - lh) * (dx ? lw : 1.f - lw);
          if (valid) {
            int idx = yi * W + xi;
            acc += wc * aw * vlev[(size_t)idx * EMBED + h * HEAD_DIM + d];
          }
        }
      }
    }
    o_s[r][h * HEAD_DIM + d] = acc;
  }
  __syncthreads();

  // ---- output projection: out = o_s @ W_out + b_out ----
  {
    float acc[QPB];
#pragma unroll
    for (int r = 0; r < QPB; ++r) acc[r] = 0.f;
    for (int k = 0; k < EMBED; ++k) {
      float w = W_out[(size_t)k * EMBED + tid];
#pragma unroll
      for (int r = 0; r < QPB; ++r) acc[r] += o_s[r][k] * w;
    }
    float bo = b_out[tid];
    for (int r = 0; r < QPB; ++r) {
      int q = q0 + r;
      if (q < LQ) out[((size_t)b * LQ + q) * EMBED + tid] = acc[r] + bo;
    }
  }
}

// ---------------------------------------------------------------------------
extern "C" void kernel_launch(void* const* d_in, const int* in_sizes, int n_in,
                              void* d_out, int out_size, void* d_ws,
                              size_t ws_size, hipStream_t stream) {
  const float* query = (const float*)d_in[0];
  const float* refpts = (const float*)d_in[1];
  const float* value = (const float*)d_in[2];
  const uint8_t* mask = (const uint8_t*)d_in[3];
  // d_in[4] = spatial_shapes (hardcoded: {100,100},{50,50},{25,25},{13,13})
  const float* W_off = (const float*)d_in[5];
  const float* b_off = (const float*)d_in[6];
  const float* W_attn = (const float*)d_in[7];
  const float* b_attn = (const float*)d_in[8];
  const float* W_val = (const float*)d_in[9];
  const float* b_val = (const float*)d_in[10];
  const float* W_out = (const float*)d_in[11];
  const float* b_out = (const float*)d_in[12];
  float* out = (float*)d_out;
  float* v_ws = (float*)d_ws;  // BS*LV*256 f32 = ~27.2 MB

  const int n_rows = BS * LV_TOTAL;
  dim3 g1((n_rows + VP_ROWS - 1) / VP_ROWS);
  value_proj_kernel<<<g1, 256, 0, stream>>>(value, mask, W_val, b_val, v_ws,
                                            n_rows);

  dim3 g2((LQ + QPB - 1) / QPB, BS);
  msda_kernel<<<g2, 256, 0, stream>>>(query, refpts, v_ws, W_off, b_off,
                                      W_attn, b_attn, W_out, b_out, out);
}

// Round 2
// 367.830 us; speedup vs baseline: 2.2630x; 2.2630x over previous
//
#include <hip/hip_runtime.h>
#include <stdint.h>

#define EMBED 256
#define HEADS 8
#define LEVELS 4
#define POINTS 4
#define HEAD_DIM 32
#define BS 2
#define LV_TOTAL 13294
#define LQ LV_TOTAL
#define TP 128 /* HEADS*LEVELS*POINTS */

#define VP_ROWS 16
#define QPB 8

// ---------------------------------------------------------------------------
// Kernel 1: v = value @ W_val + b_val, masked.  Output layout (b, lv, 256).
// float4 k-blocking: per k4 -> 4 coalesced W loads + 16 ds_read_b128 + 64 FMA.
// ---------------------------------------------------------------------------
__global__ __launch_bounds__(256) void value_proj_kernel(
    const float* __restrict__ value, const uint8_t* __restrict__ mask,
    const float* __restrict__ W_val, const float* __restrict__ b_val,
    float* __restrict__ v_out, int n_rows) {
  __shared__ float a_s[VP_ROWS][EMBED];
  const int row0 = blockIdx.x * VP_ROWS;
  const int tid = threadIdx.x;

  for (int r = 0; r < VP_ROWS; ++r) {
    int row = row0 + r;
    a_s[r][tid] = (row < n_rows) ? value[(size_t)row * EMBED + tid] : 0.f;
  }
  __syncthreads();

  float acc[VP_ROWS];
#pragma unroll
  for (int r = 0; r < VP_ROWS; ++r) acc[r] = 0.f;

  const float4* a4 = (const float4*)&a_s[0][0];  // [VP_ROWS][64]
  for (int k4 = 0; k4 < EMBED / 4; ++k4) {
    float w0 = W_val[(size_t)(k4 * 4 + 0) * EMBED + tid];
    float w1 = W_val[(size_t)(k4 * 4 + 1) * EMBED + tid];
    float w2 = W_val[(size_t)(k4 * 4 + 2) * EMBED + tid];
    float w3 = W_val[(size_t)(k4 * 4 + 3) * EMBED + tid];
#pragma unroll
    for (int r = 0; r < VP_ROWS; ++r) {
      float4 a = a4[r * 64 + k4];
      acc[r] += a.x * w0 + a.y * w1 + a.z * w2 + a.w * w3;
    }
  }

  const float bias = b_val[tid];
  for (int r = 0; r < VP_ROWS; ++r) {
    int row = row0 + r;
    if (row < n_rows) {
      float o = acc[r] + bias;
      if (mask[row]) o = 0.f;
      v_out[(size_t)row * EMBED + tid] = o;
    }
  }
}

// ---------------------------------------------------------------------------
// Kernel 2: fused offsets/attn/softmax/meta-precompute/gather/out-projection.
// One block = QPB(8) queries of one batch, 256 threads.
// Phases:
//  1. stage q rows + ref points
//  2. off GEMM (acc stays in REGISTERS, col = tid), attn GEMM (all 256 thr)
//  3. softmax(16) per (q,head)
//  4. meta: lane pair exchanges x/y via shfl_xor; each thread computes 4
//     samples' 4 clamped corner idx (ushort4) + premult weights (float4),
//     written to XOR-swizzled LDS  -> sampling math done ONCE per sample
//  5. gather: thread=(h,dim-quad); per sample: 2 LDS broadcast reads +
//     4 global_load_dwordx4 + 16 FMA. o written into q_s region (reuse).
//  6. out GEMM from o_s.
// ---------------------------------------------------------------------------
__global__ __launch_bounds__(256, 4) void msda_kernel(
    const float* __restrict__ query, const float* __restrict__ refpts,
    const float* __restrict__ v,  // (BS, LV, 256) projected value
    const float* __restrict__ W_off, const float* __restrict__ b_off,
    const float* __restrict__ W_attn, const float* __restrict__ b_attn,
    const float* __restrict__ W_out, const float* __restrict__ b_out,
    float* __restrict__ out) {
  __shared__ float q_s[QPB][EMBED];  // reused as o_s in phases 5-6
  __shared__ float attn_s[QPB][TP];
  __shared__ float ref_s[QPB][LEVELS][2];
  __shared__ ushort4 meta_idx[QPB][TP];  // 8 KB
  __shared__ float4 meta_w[QPB][TP];     // 16 KB

  const int b = blockIdx.y;
  const int q0 = blockIdx.x * QPB;
  const int tid = threadIdx.x;

  // ---- phase 1: stage query rows + reference points ----
  for (int r = 0; r < QPB; ++r) {
    int q = q0 + r;
    q_s[r][tid] = (q < LQ) ? query[((size_t)b * LQ + q) * EMBED + tid] : 0.f;
  }
  if (tid < QPB * LEVELS * 2) {
    int r = tid / (LEVELS * 2);
    int rem = tid % (LEVELS * 2);
    int q = q0 + r;
    ref_s[r][rem / 2][rem % 2] =
        (q < LQ) ? refpts[((size_t)b * LQ + q) * (LEVELS * 2) + rem] : 0.f;
  }
  __syncthreads();

  const float4* q4p = (const float4*)&q_s[0][0];  // [QPB][64]

  // ---- phase 2a: offset GEMM, accumulators stay in registers ----
  float accOff[QPB];
#pragma unroll
  for (int r = 0; r < QPB; ++r) accOff[r] = 0.f;
  for (int k4 = 0; k4 < EMBED / 4; ++k4) {
    float w0 = W_off[(size_t)(k4 * 4 + 0) * (TP * 2) + tid];
    float w1 = W_off[(size_t)(k4 * 4 + 1) * (TP * 2) + tid];
    float w2 = W_off[(size_t)(k4 * 4 + 2) * (TP * 2) + tid];
    float w3 = W_off[(size_t)(k4 * 4 + 3) * (TP * 2) + tid];
#pragma unroll
    for (int r = 0; r < QPB; ++r) {
      float4 q4 = q4p[r * 64 + k4];
      accOff[r] += q4.x * w0 + q4.y * w1 + q4.z * w2 + q4.w * w3;
    }
  }
  {
    float bo = b_off[tid];
#pragma unroll
    for (int r = 0; r < QPB; ++r) accOff[r] += bo;
  }

  // ---- phase 2b: attn GEMM, all 256 threads: j=tid&127, half of r each ----
  {
    const int j = tid & (TP - 1);
    const int rh = tid >> 7;  // 0 or 1
    float accA[4] = {0.f, 0.f, 0.f, 0.f};
    for (int k4 = 0; k4 < EMBED / 4; ++k4) {
      float w0 = W_attn[(size_t)(k4 * 4 + 0) * TP + j];
      float w1 = W_attn[(size_t)(k4 * 4 + 1) * TP + j];
      float w2 = W_attn[(size_t)(k4 * 4 + 2) * TP + j];
      float w3 = W_attn[(size_t)(k4 * 4 + 3) * TP + j];
#pragma unroll
      for (int rr = 0; rr < 4; ++rr) {
        float4 q4 = q4p[(rh * 4 + rr) * 64 + k4];
        accA[rr] += q4.x * w0 + q4.y * w1 + q4.z * w2 + q4.w * w3;
      }
    }
    float ba = b_attn[j];
#pragma unroll
    for (int rr = 0; rr < 4; ++rr) attn_s[rh * 4 + rr][j] = accA[rr] + ba;
  }
  __syncthreads();

  // ---- phase 3: softmax over 16 per (query, head) ----
  if (tid < QPB * HEADS) {
    int r = tid / HEADS, h = tid % HEADS;
    float* a = &attn_s[r][h * 16];
    float m = a[0];
#pragma unroll
    for (int i = 1; i < 16; ++i) m = fmaxf(m, a[i]);
    float e[16];
    float s = 0.f;
#pragma unroll
    for (int i = 0; i < 16; ++i) {
      e[i] = __expf(a[i] - m);
      s += e[i];
    }
    float inv = 1.f / s;
#pragma unroll
    for (int i = 0; i < 16; ++i) a[i] = e[i] * inv;
  }
  __syncthreads();

  // ---- phase 4: meta precompute (idx4 + premultiplied weights) ----
  {
    float other[QPB];
#pragma unroll
    for (int r = 0; r < QPB; ++r) other[r] = __shfl_xor(accOff[r], 1, 64);

    const int s = tid >> 1;  // sample 0..127 == h*16 + l*4 + p
    const int isOdd = tid & 1;
    const int l = (s >> 2) & 3;
    const int W = (l == 0) ? 100 : (l == 1) ? 50 : (l == 2) ? 25 : 13;
    const int base = (l == 0) ? 0 : (l == 1) ? 10000 : (l == 2) ? 12500 : 13125;
    const float fW = (float)W;
    const int posx = s ^ ((s >> 4) & 7);  // swizzle: spread h-groups over banks

#pragma unroll
    for (int rr = 0; rr < 4; ++rr) {
      int r = isOdd ? (4 + rr) : rr;
      float ox = isOdd ? other[r] : accOff[r];
      float oy = isOdd ? accOff[r] : other[r];
      float rx = ref_s[r][l][0];
      float ry = ref_s[r][l][1];
      float aw = attn_s[r][s];
      float x = fmaf(rx, fW, ox) - 0.5f;
      float y = fmaf(ry, fW, oy) - 0.5f;  // H == W for all levels
      float x0f = floorf(x), y0f = floorf(y);
      float lw = x - x0f, lh = y - y0f;
      int x0 = (int)x0f, y0 = (int)y0f;
      int x1 = x0 + 1, y1 = y0 + 1;
      bool x0v = (x0 >= 0) && (x0 < W);
      bool x1v = (x1 >= 0) && (x1 < W);
      bool y0v = (y0 >= 0) && (y0 < W);
      bool y1v = (y1 >= 0) && (y1 < W);
      int xc0 = min(max(x0, 0), W - 1), xc1 = min(max(x1, 0), W - 1);
      int yc0 = min(max(y0, 0), W - 1), yc1 = min(max(y1, 0), W - 1);
      float w00 = (1.f - lh) * (1.f - lw) * aw;
      float w01 = (1.f - lh) * lw * aw;
      float w10 = lh * (1.f - lw) * aw;
      float w11 = lh * lw * aw;
      meta_w[r][posx] =
          make_float4((x0v && y0v) ? w00 : 0.f, (x1v && y0v) ? w01 : 0.f,
                      (x0v && y1v) ? w10 : 0.f, (x1v && y1v) ? w11 : 0.f);
      meta_idx[r][posx] = make_ushort4(
          (unsigned short)(base + yc0 * W + xc0),
          (unsigned short)(base + yc0 * W + xc1),
          (unsigned short)(base + yc1 * W + xc0),
          (unsigned short)(base + yc1 * W + xc1));
    }
  }
  __syncthreads();

  // ---- phase 5: gather.  thread = (wave ry, head h, dim-quad t) ----
  {
    const int ry = tid >> 6;        // 0..3 (wave id)
    const int h = (tid >> 3) & 7;   // head
    const int t = tid & 7;          // dim quad
    const float* vb =
        v + (size_t)b * LV_TOTAL * EMBED + h * HEAD_DIM + t * 4;
    float* o_s = &q_s[0][0];  // q_s no longer needed

#pragma unroll
    for (int qi = 0; qi < 2; ++qi) {
      const int r = ry + qi * 4;
      float ax = 0.f, ay = 0.f, az = 0.f, aw_ = 0.f;
#pragma unroll
      for (int ss = 0; ss < 16; ++ss) {
        int pos = (h * 16 + ss) ^ h;  // same swizzle as writer
        ushort4 i4 = meta_idx[r][pos];
        float4 w4 = meta_w[r][pos];
        float4 v0 = *(const float4*)(vb + ((int)i4.x << 8));
        float4 v1 = *(const float4*)(vb + ((int)i4.y << 8));
        float4 v2 = *(const float4*)(vb + ((int)i4.z << 8));
        float4 v3 = *(const float4*)(vb + ((int)i4.w << 8));
        ax += w4.x * v0.x + w4.y * v1.x + w4.z * v2.x + w4.w * v3.x;
        ay += w4.x * v0.y + w4.y * v1.y + w4.z * v2.y + w4.w * v3.y;
        az += w4.x * v0.z + w4.y * v1.z + w4.z * v2.z + w4.w * v3.z;
        aw_ += w4.x * v0.w + w4.y * v1.w + w4.z * v2.w + w4.w * v3.w;
      }
      *(float4*)(o_s + r * EMBED + h * HEAD_DIM + t * 4) =
          make_float4(ax, ay, az, aw_);
    }
  }
  __syncthreads();

  // ---- phase 6: output projection ----
  {
    const float4* o4 = (const float4*)&q_s[0][0];  // [QPB][64]
    float acc[QPB];
#pragma unroll
    for (int r = 0; r < QPB; ++r) acc[r] = 0.f;
    for (int k4 = 0; k4 < EMBED / 4; ++k4) {
      float w0 = W_out[(size_t)(k4 * 4 + 0) * EMBED + tid];
      float w1 = W_out[(size_t)(k4 * 4 + 1) * EMBED + tid];
      float w2 = W_out[(size_t)(k4 * 4 + 2) * EMBED + tid];
      float w3 = W_out[(size_t)(k4 * 4 + 3) * EMBED + tid];
#pragma unroll
      for (int r = 0; r < QPB; ++r) {
        float4 o = o4[r * 64 + k4];
        acc[r] += o.x * w0 + o.y * w1 + o.z * w2 + o.w * w3;
      }
    }
    float bo = b_out[tid];
    for (int r = 0; r < QPB; ++r) {
      int q = q0 + r;
      if (q < LQ) out[((size_t)b * LQ + q) * EMBED + tid] = acc[r] + bo;
    }
  }
}

// ---------------------------------------------------------------------------
extern "C" void kernel_launch(void* const* d_in, const int* in_sizes, int n_in,
                              void* d_out, int out_size, void* d_ws,
                              size_t ws_size, hipStream_t stream) {
  const float* query = (const float*)d_in[0];
  const float* refpts = (const float*)d_in[1];
  const float* value = (const float*)d_in[2];
  const uint8_t* mask = (const uint8_t*)d_in[3];
  // d_in[4] = spatial_shapes (hardcoded: {100,100},{50,50},{25,25},{13,13})
  const float* W_off = (const float*)d_in[5];
  const float* b_off = (const float*)d_in[6];
  const float* W_attn = (const float*)d_in[7];
  const float* b_attn = (const float*)d_in[8];
  const float* W_val = (const float*)d_in[9];
  const float* b_val = (const float*)d_in[10];
  const float* W_out = (const float*)d_in[11];
  const float* b_out = (const float*)d_in[12];
  float* out = (float*)d_out;
  float* v_ws = (float*)d_ws;  // BS*LV*256 f32 = ~27.2 MB

  const int n_rows = BS * LV_TOTAL;
  dim3 g1((n_rows + VP_ROWS - 1) / VP_ROWS);
  value_proj_kernel<<<g1, 256, 0, stream>>>(value, mask, W_val, b_val, v_ws,
                                            n_rows);

  dim3 g2((LQ + QPB - 1) / QPB, BS);
  msda_kernel<<<g2, 256, 0, stream>>>(query, refpts, v_ws, W_off, b_off,
                                      W_attn, b_attn, W_out, b_out, out);
}

// Round 3
// 250.219 us; speedup vs baseline: 3.3266x; 1.4700x over previous
//
#include <hip/hip_runtime.h>
#include <hip/hip_bf16.h>
#include <stdint.h>

#define EMBED 256
#define HEADS 8
#define LEVELS 4
#define POINTS 4
#define HEAD_DIM 32
#define BS 2
#define LV_TOTAL 13294
#define LQ LV_TOTAL
#define TP 128 /* HEADS*LEVELS*POINTS */
#define M_ROWS (BS * LV_TOTAL) /* 26588 */
#define QPB 8

typedef __attribute__((ext_vector_type(8))) short bf16x8;
typedef __attribute__((ext_vector_type(4))) float f32x4;

static __device__ __forceinline__ unsigned short f2bf(float x) {
  __hip_bfloat16 h = __float2bfloat16(x);
  return *reinterpret_cast<unsigned short*>(&h);
}
static __device__ __forceinline__ float bf2f(unsigned short u) {
  return __uint_as_float(((unsigned int)u) << 16);
}

// ---------------------------------------------------------------------------
// prep_wt: transpose + convert all weight matrices to bf16 WT[n][k] layout.
// blocks: [0,256) W_val | [256,512) W_off | [512,640) W_attn | [640,896) W_out
// ---------------------------------------------------------------------------
__global__ __launch_bounds__(256) void prep_wt_kernel(
    const float* __restrict__ W_val, const float* __restrict__ W_off,
    const float* __restrict__ W_attn, const float* __restrict__ W_out,
    unsigned short* __restrict__ WT_val, unsigned short* __restrict__ WT_oa,
    unsigned short* __restrict__ WT_out) {
  const int bid = blockIdx.x;
  const int k = threadIdx.x;  // 0..255
  const float* src;
  unsigned short* dst;
  int n, N_src;
  if (bid < 256) {
    src = W_val; dst = WT_val; n = bid; N_src = 256;
  } else if (bid < 512) {
    src = W_off; dst = WT_oa; n = bid - 256; N_src = 256;
  } else if (bid < 640) {
    src = W_attn; dst = WT_oa + 256 * 256; n = bid - 512; N_src = 128;
  } else {
    src = W_out; dst = WT_out; n = bid - 640; N_src = 256;
  }
  dst[n * 256 + k] = f2bf(src[(size_t)k * N_src + n]);
}

// ---------------------------------------------------------------------------
// LDS-free MFMA GEMM: C(MxN) = A(Mx256) @ B(256xN) + bias.
// B passed pre-transposed+bf16 as BT[n][k].  256 threads = 4 waves stacked
// along M; each wave computes a 16x64 tile via 8 k-steps of 16x16x32 MFMA.
// A-frag: lane row=l&15, k=(l>>4)*8 (+kk*32), 8 contiguous -> direct load.
// ---------------------------------------------------------------------------
template <bool A_BF16, bool OUT_BF16, bool MASKED, bool SPLIT_BIAS>
__global__ __launch_bounds__(256) void mfma_gemm_kernel(
    const void* __restrict__ Av, const unsigned short* __restrict__ BT,
    const float* __restrict__ bias0, const float* __restrict__ bias1,
    const uint8_t* __restrict__ mask, void* __restrict__ Cv, int M, int N) {
  const int tid = threadIdx.x;
  const int wave = tid >> 6;
  const int lane = tid & 63;
  const int lr = lane & 15;
  const int kq = lane >> 4;  // 0..3
  const int row0 = blockIdx.x * 64 + wave * 16;
  const int col0 = blockIdx.y * 64;
  const int arow = min(row0 + lr, M - 1);

  f32x4 acc[4];
#pragma unroll
  for (int c = 0; c < 4; ++c) acc[c] = (f32x4){0.f, 0.f, 0.f, 0.f};

  const float* Af = (const float*)Av;
  const unsigned short* Ab = (const unsigned short*)Av;

#pragma unroll
  for (int kk = 0; kk < 8; ++kk) {
    const int k0 = kk * 32 + kq * 8;
    bf16x8 a;
    if constexpr (A_BF16) {
      a = *(const bf16x8*)(Ab + (size_t)arow * 256 + k0);
    } else {
      float4 a0 = *(const float4*)(Af + (size_t)arow * 256 + k0);
      float4 a1 = *(const float4*)(Af + (size_t)arow * 256 + k0 + 4);
      a[0] = (short)f2bf(a0.x); a[1] = (short)f2bf(a0.y);
      a[2] = (short)f2bf(a0.z); a[3] = (short)f2bf(a0.w);
      a[4] = (short)f2bf(a1.x); a[5] = (short)f2bf(a1.y);
      a[6] = (short)f2bf(a1.z); a[7] = (short)f2bf(a1.w);
    }
#pragma unroll
    for (int c = 0; c < 4; ++c) {
      bf16x8 bfrag =
          *(const bf16x8*)(BT + (size_t)(col0 + c * 16 + lr) * 256 + k0);
      acc[c] = __builtin_amdgcn_mfma_f32_16x16x32_bf16(a, bfrag, acc[c], 0, 0, 0);
    }
  }

  // epilogue: D col = lane&15, row = (lane>>4)*4 + i   [m89-verified]
#pragma unroll
  for (int c = 0; c < 4; ++c) {
    const int col = col0 + c * 16 + lr;
    float bv;
    if constexpr (SPLIT_BIAS)
      bv = (col < 256) ? bias0[col] : bias1[col - 256];
    else
      bv = bias0[col];
#pragma unroll
    for (int i = 0; i < 4; ++i) {
      const int row = row0 + kq * 4 + i;
      if (row < M) {
        float o = acc[c][i] + bv;
        if constexpr (MASKED) {
          if (mask[row]) o = 0.f;
        }
        if constexpr (OUT_BF16)
          ((unsigned short*)Cv)[(size_t)row * N + col] = f2bf(o);
        else
          ((float*)Cv)[(size_t)row * N + col] = o;
      }
    }
  }
}

// ---------------------------------------------------------------------------
// gather_kernel: per block QPB(8) queries of one batch, 256 threads.
// Reads precomputed off/attn (bf16), does softmax + meta precompute + f32-v
// bilinear gather; writes o (bf16) for the final MFMA out-projection.
// ---------------------------------------------------------------------------
__global__ __launch_bounds__(256) void gather_kernel(
    const float* __restrict__ refpts,
    const float* __restrict__ v,            // f32 (BS, LV, 256)
    const unsigned short* __restrict__ oa,  // bf16 (BS*LQ, 384) [off|attn]
    unsigned short* __restrict__ o_out) {   // bf16 (BS*LQ, 256)
  __shared__ float attn_s[QPB][TP];
  __shared__ float ref_s[QPB][LEVELS][2];
  __shared__ ushort4 meta_idx[QPB][TP];  // 8 KB
  __shared__ float4 meta_w[QPB][TP];     // 16 KB

  const int b = blockIdx.y;
  const int q0 = blockIdx.x * QPB;
  const int tid = threadIdx.x;

  // ---- load offsets (col = tid, one per query, stays in registers) ----
  float accOff[QPB];
#pragma unroll
  for (int r = 0; r < QPB; ++r) {
    int q = min(q0 + r, LQ - 1);
    size_t row = (size_t)b * LQ + q;
    accOff[r] = bf2f(oa[row * 384 + tid]);
  }
  // ---- load attn logits to LDS ----
#pragma unroll
  for (int i = 0; i < 4; ++i) {
    int idx = i * 256 + tid;  // 0..1023
    int r = idx >> 7, col = idx & 127;
    int q = min(q0 + r, LQ - 1);
    size_t row = (size_t)b * LQ + q;
    attn_s[r][col] = bf2f(oa[row * 384 + 256 + col]);
  }
  // ---- reference points ----
  if (tid < QPB * LEVELS * 2) {
    int r = tid / (LEVELS * 2);
    int rem = tid % (LEVELS * 2);
    int q = min(q0 + r, LQ - 1);
    ref_s[r][rem / 2][rem % 2] =
        refpts[((size_t)b * LQ + q) * (LEVELS * 2) + rem];
  }
  __syncthreads();

  // ---- softmax over 16 per (query, head) ----
  if (tid < QPB * HEADS) {
    int r = tid / HEADS, h = tid % HEADS;
    float* a = &attn_s[r][h * 16];
    float m = a[0];
#pragma unroll
    for (int i = 1; i < 16; ++i) m = fmaxf(m, a[i]);
    float e[16];
    float s = 0.f;
#pragma unroll
    for (int i = 0; i < 16; ++i) {
      e[i] = __expf(a[i] - m);
      s += e[i];
    }
    float inv = 1.f / s;
#pragma unroll
    for (int i = 0; i < 16; ++i) a[i] = e[i] * inv;
  }
  __syncthreads();

  // ---- meta precompute (clamped corner idx4 + premultiplied weights) ----
  {
    float other[QPB];
#pragma unroll
    for (int r = 0; r < QPB; ++r) other[r] = __shfl_xor(accOff[r], 1, 64);

    const int s = tid >> 1;  // sample 0..127 == h*16 + l*4 + p
    const int isOdd = tid & 1;
    const int l = (s >> 2) & 3;
    const int W = (l == 0) ? 100 : (l == 1) ? 50 : (l == 2) ? 25 : 13;
    const int base = (l == 0) ? 0 : (l == 1) ? 10000 : (l == 2) ? 12500 : 13125;
    const float fW = (float)W;
    const int posx = s ^ ((s >> 4) & 7);  // bank swizzle, involution

#pragma unroll
    for (int rr = 0; rr < 4; ++rr) {
      int r = isOdd ? (4 + rr) : rr;
      float ox = isOdd ? other[r] : accOff[r];
      float oy = isOdd ? accOff[r] : other[r];
      float rx = ref_s[r][l][0];
      float ry = ref_s[r][l][1];
      float aw = attn_s[r][s];
      float x = fmaf(rx, fW, ox) - 0.5f;
      float y = fmaf(ry, fW, oy) - 0.5f;  // H == W for all levels
      float x0f = floorf(x), y0f = floorf(y);
      float lw = x - x0f, lh = y - y0f;
      int x0 = (int)x0f, y0 = (int)y0f;
      int x1 = x0 + 1, y1 = y0 + 1;
      bool x0v = (x0 >= 0) && (x0 < W);
      bool x1v = (x1 >= 0) && (x1 < W);
      bool y0v = (y0 >= 0) && (y0 < W);
      bool y1v = (y1 >= 0) && (y1 < W);
      int xc0 = min(max(x0, 0), W - 1), xc1 = min(max(x1, 0), W - 1);
      int yc0 = min(max(y0, 0), W - 1), yc1 = min(max(y1, 0), W - 1);
      float w00 = (1.f - lh) * (1.f - lw) * aw;
      float w01 = (1.f - lh) * lw * aw;
      float w10 = lh * (1.f - lw) * aw;
      float w11 = lh * lw * aw;
      meta_w[r][posx] =
          make_float4((x0v && y0v) ? w00 : 0.f, (x1v && y0v) ? w01 : 0.f,
                      (x0v && y1v) ? w10 : 0.f, (x1v && y1v) ? w11 : 0.f);
      meta_idx[r][posx] = make_ushort4(
          (unsigned short)(base + yc0 * W + xc0),
          (unsigned short)(base + yc0 * W + xc1),
          (unsigned short)(base + yc1 * W + xc0),
          (unsigned short)(base + yc1 * W + xc1));
    }
  }
  __syncthreads();

  // ---- gather: thread = (wave r, head h, dim-quad t) ----
  {
    const int ry = tid >> 6;       // 0..3 (wave id)
    const int h = (tid >> 3) & 7;  // head
    const int t = tid & 7;         // dim quad
    const float* vb = v + (size_t)b * LV_TOTAL * EMBED + h * HEAD_DIM + t * 4;

#pragma unroll
    for (int qi = 0; qi < 2; ++qi) {
      const int r = ry + qi * 4;
      float ax = 0.f, ay = 0.f, az = 0.f, aw_ = 0.f;
#pragma unroll
      for (int ss = 0; ss < 16; ++ss) {
        int pos = (h * 16 + ss) ^ h;  // same swizzle as writer
        ushort4 i4 = meta_idx[r][pos];
        float4 w4 = meta_w[r][pos];
        float4 v0 = *(const float4*)(vb + ((int)i4.x << 8));
        float4 v1 = *(const float4*)(vb + ((int)i4.y << 8));
        float4 v2 = *(const float4*)(vb + ((int)i4.z << 8));
        float4 v3 = *(const float4*)(vb + ((int)i4.w << 8));
        ax += w4.x * v0.x + w4.y * v1.x + w4.z * v2.x + w4.w * v3.x;
        ay += w4.x * v0.y + w4.y * v1.y + w4.z * v2.y + w4.w * v3.y;
        az += w4.x * v0.z + w4.y * v1.z + w4.z * v2.z + w4.w * v3.z;
        aw_ += w4.x * v0.w + w4.y * v1.w + w4.z * v2.w + w4.w * v3.w;
      }
      const int q = q0 + r;
      if (q < LQ) {
        uint2 pk;
        pk.x = (unsigned int)f2bf(ax) | ((unsigned int)f2bf(ay) << 16);
        pk.y = (unsigned int)f2bf(az) | ((unsigned int)f2bf(aw_) << 16);
        *(uint2*)(o_out + ((size_t)b * LQ + q) * EMBED + h * HEAD_DIM + t * 4) =
            pk;
      }
    }
  }
}

// ---------------------------------------------------------------------------
extern "C" void kernel_launch(void* const* d_in, const int* in_sizes, int n_in,
                              void* d_out, int out_size, void* d_ws,
                              size_t ws_size, hipStream_t stream) {
  const float* query = (const float*)d_in[0];
  const float* refpts = (const float*)d_in[1];
  const float* value = (const float*)d_in[2];
  const uint8_t* mask = (const uint8_t*)d_in[3];
  // d_in[4] = spatial_shapes (hardcoded: {100,100},{50,50},{25,25},{13,13})
  const float* W_off = (const float*)d_in[5];
  const float* b_off = (const float*)d_in[6];
  const float* W_attn = (const float*)d_in[7];
  const float* b_attn = (const float*)d_in[8];
  const float* W_val = (const float*)d_in[9];
  const float* b_val = (const float*)d_in[10];
  const float* W_out = (const float*)d_in[11];
  const float* b_out = (const float*)d_in[12];
  float* out = (float*)d_out;

  // ws layout (bytes)
  char* ws = (char*)d_ws;
  float* v_ws = (float*)ws;                       // f32 [26588][256] = 27,226,112
  unsigned short* oa_ws =
      (unsigned short*)(ws + 27226112);           // bf16 [26588][384] = 20,419,584
  unsigned short* o_ws =
      (unsigned short*)(ws + 27226112 + 20419584);  // bf16 [26588][256] = 13,613,056
  unsigned short* wt_val =
      (unsigned short*)(ws + 27226112 + 20419584 + 13613056);  // 131072
  unsigned short* wt_oa = wt_val + 256 * 256;                  // 196608
  unsigned short* wt_out = wt_oa + 384 * 256;                  // 131072

  prep_wt_kernel<<<896, 256, 0, stream>>>(W_val, W_off, W_attn, W_out, wt_val,
                                          wt_oa, wt_out);

  const int MB = (M_ROWS + 63) / 64;  // 416
  // v = value @ W_val + b_val, masked  (f32 out)
  mfma_gemm_kernel<false, false, true, false><<<dim3(MB, 4), 256, 0, stream>>>(
      value, wt_val, b_val, nullptr, mask, v_ws, M_ROWS, 256);
  // [off|attn] = query @ [W_off|W_attn] + [b_off|b_attn]  (bf16 out)
  mfma_gemm_kernel<false, true, false, true><<<dim3(MB, 6), 256, 0, stream>>>(
      query, wt_oa, b_off, b_attn, nullptr, oa_ws, M_ROWS, 384);

  dim3 g2((LQ + QPB - 1) / QPB, BS);
  gather_kernel<<<g2, 256, 0, stream>>>(refpts, v_ws, oa_ws, o_ws);

  // out = o @ W_out + b_out  (f32 out)
  mfma_gemm_kernel<true, false, false, false><<<dim3(MB, 4), 256, 0, stream>>>(
      o_ws, wt_out, b_out, nullptr, nullptr, out, M_ROWS, 256);
}

// Round 4
// 230.360 us; speedup vs baseline: 3.6134x; 1.0862x over previous
//
#include <hip/hip_runtime.h>
#include <hip/hip_bf16.h>
#include <stdint.h>

#define EMBED 256
#define HEADS 8
#define LEVELS 4
#define POINTS 4
#define HEAD_DIM 32
#define BS 2
#define LV_TOTAL 13294
#define LQ LV_TOTAL
#define TP 128 /* HEADS*LEVELS*POINTS */
#define M_ROWS (BS * LV_TOTAL) /* 26588 */
#define QPB 8

typedef __attribute__((ext_vector_type(8))) short bf16x8;
typedef __attribute__((ext_vector_type(4))) float f32x4;

static __device__ __forceinline__ unsigned short f2bf(float x) {
  __hip_bfloat16 h = __float2bfloat16(x);
  return *reinterpret_cast<unsigned short*>(&h);
}
static __device__ __forceinline__ float bf2f(unsigned short u) {
  return __uint_as_float(((unsigned int)u) << 16);
}

// ---------------------------------------------------------------------------
// prep_wt: transpose + convert all weight matrices to bf16 WT[n][k] layout.
// blocks: [0,256) W_val | [256,512) W_off | [512,640) W_attn | [640,896) W_out
// ---------------------------------------------------------------------------
__global__ __launch_bounds__(256) void prep_wt_kernel(
    const float* __restrict__ W_val, const float* __restrict__ W_off,
    const float* __restrict__ W_attn, const float* __restrict__ W_out,
    unsigned short* __restrict__ WT_val, unsigned short* __restrict__ WT_oa,
    unsigned short* __restrict__ WT_out) {
  const int bid = blockIdx.x;
  const int k = threadIdx.x;  // 0..255
  const float* src;
  unsigned short* dst;
  int n, N_src;
  if (bid < 256) {
    src = W_val; dst = WT_val; n = bid; N_src = 256;
  } else if (bid < 512) {
    src = W_off; dst = WT_oa; n = bid - 256; N_src = 256;
  } else if (bid < 640) {
    src = W_attn; dst = WT_oa + 256 * 256; n = bid - 512; N_src = 128;
  } else {
    src = W_out; dst = WT_out; n = bid - 640; N_src = 256;
  }
  dst[n * 256 + k] = f2bf(src[(size_t)k * N_src + n]);
}

// ---------------------------------------------------------------------------
// Row-block MFMA GEMM: C(M x N) = A(M x 256) @ B(256 x N) + bias.
// B pre-transposed bf16 BT[n][k]. One block = 32 rows x N cols, NW waves;
// wave w owns cols [w*64, w*64+64) with TWO 16-row A-frags -> 64 MFMA/wave,
// B-frag reuse x2, A-frag reuse x4, A read exactly once (no col-strip loop).
// ---------------------------------------------------------------------------
template <int NW, bool A_BF16, bool OUT_BF16, bool MASKED, bool SPLIT_BIAS>
__global__ __launch_bounds__(64 * NW) void gemm_rowblock_kernel(
    const void* __restrict__ Av, const unsigned short* __restrict__ BT,
    const float* __restrict__ bias0, const float* __restrict__ bias1,
    const uint8_t* __restrict__ mask, void* __restrict__ Cv, int M) {
  constexpr int N = NW * 64;
  const int tid = threadIdx.x;
  const int wave = tid >> 6;
  const int lane = tid & 63;
  const int lr = lane & 15;
  const int kq = lane >> 4;  // 0..3
  const int row0 = blockIdx.x * 32;
  const int col0 = wave * 64;
  const int ar0 = min(row0 + lr, M - 1);
  const int ar1 = min(row0 + 16 + lr, M - 1);

  f32x4 acc[2][4];
#pragma unroll
  for (int ri = 0; ri < 2; ++ri)
#pragma unroll
    for (int c = 0; c < 4; ++c) acc[ri][c] = (f32x4){0.f, 0.f, 0.f, 0.f};

  const float* Af = (const float*)Av;
  const unsigned short* Ab = (const unsigned short*)Av;

#pragma unroll
  for (int kk = 0; kk < 8; ++kk) {
    const int k0 = kk * 32 + kq * 8;
    bf16x8 a0, a1;
    if constexpr (A_BF16) {
      a0 = *(const bf16x8*)(Ab + (size_t)ar0 * 256 + k0);
      a1 = *(const bf16x8*)(Ab + (size_t)ar1 * 256 + k0);
    } else {
      float4 p0 = *(const float4*)(Af + (size_t)ar0 * 256 + k0);
      float4 p1 = *(const float4*)(Af + (size_t)ar0 * 256 + k0 + 4);
      float4 p2 = *(const float4*)(Af + (size_t)ar1 * 256 + k0);
      float4 p3 = *(const float4*)(Af + (size_t)ar1 * 256 + k0 + 4);
      a0[0] = (short)f2bf(p0.x); a0[1] = (short)f2bf(p0.y);
      a0[2] = (short)f2bf(p0.z); a0[3] = (short)f2bf(p0.w);
      a0[4] = (short)f2bf(p1.x); a0[5] = (short)f2bf(p1.y);
      a0[6] = (short)f2bf(p1.z); a0[7] = (short)f2bf(p1.w);
      a1[0] = (short)f2bf(p2.x); a1[1] = (short)f2bf(p2.y);
      a1[2] = (short)f2bf(p2.z); a1[3] = (short)f2bf(p2.w);
      a1[4] = (short)f2bf(p3.x); a1[5] = (short)f2bf(p3.y);
      a1[6] = (short)f2bf(p3.z); a1[7] = (short)f2bf(p3.w);
    }
#pragma unroll
    for (int c = 0; c < 4; ++c) {
      bf16x8 bfrag =
          *(const bf16x8*)(BT + (size_t)(col0 + c * 16 + lr) * 256 + k0);
      acc[0][c] =
          __builtin_amdgcn_mfma_f32_16x16x32_bf16(a0, bfrag, acc[0][c], 0, 0, 0);
      acc[1][c] =
          __builtin_amdgcn_mfma_f32_16x16x32_bf16(a1, bfrag, acc[1][c], 0, 0, 0);
    }
  }

  // epilogue: D col = lane&15, row = (lane>>4)*4 + i   [m89-verified]
#pragma unroll
  for (int c = 0; c < 4; ++c) {
    const int col = col0 + c * 16 + lr;
    float bv;
    if constexpr (SPLIT_BIAS)
      bv = (col < 256) ? bias0[col] : bias1[col - 256];
    else
      bv = bias0[col];
#pragma unroll
    for (int ri = 0; ri < 2; ++ri) {
#pragma unroll
      for (int i = 0; i < 4; ++i) {
        const int row = row0 + ri * 16 + kq * 4 + i;
        if (row < M) {
          float o = acc[ri][c][i] + bv;
          if constexpr (MASKED) {
            if (mask[row]) o = 0.f;
          }
          if constexpr (OUT_BF16)
            ((unsigned short*)Cv)[(size_t)row * N + col] = f2bf(o);
          else
            ((float*)Cv)[(size_t)row * N + col] = o;
        }
      }
    }
  }
}

// ---------------------------------------------------------------------------
// gather_kernel: per block QPB(8) queries of one batch, 256 threads.
// (unchanged from round 3)
// ---------------------------------------------------------------------------
__global__ __launch_bounds__(256) void gather_kernel(
    const float* __restrict__ refpts,
    const float* __restrict__ v,            // f32 (BS, LV, 256)
    const unsigned short* __restrict__ oa,  // bf16 (BS*LQ, 384) [off|attn]
    unsigned short* __restrict__ o_out) {   // bf16 (BS*LQ, 256)
  __shared__ float attn_s[QPB][TP];
  __shared__ float ref_s[QPB][LEVELS][2];
  __shared__ ushort4 meta_idx[QPB][TP];  // 8 KB
  __shared__ float4 meta_w[QPB][TP];     // 16 KB

  const int b = blockIdx.y;
  const int q0 = blockIdx.x * QPB;
  const int tid = threadIdx.x;

  // ---- load offsets (col = tid, one per query, stays in registers) ----
  float accOff[QPB];
#pragma unroll
  for (int r = 0; r < QPB; ++r) {
    int q = min(q0 + r, LQ - 1);
    size_t row = (size_t)b * LQ + q;
    accOff[r] = bf2f(oa[row * 384 + tid]);
  }
  // ---- load attn logits to LDS ----
#pragma unroll
  for (int i = 0; i < 4; ++i) {
    int idx = i * 256 + tid;  // 0..1023
    int r = idx >> 7, col = idx & 127;
    int q = min(q0 + r, LQ - 1);
    size_t row = (size_t)b * LQ + q;
    attn_s[r][col] = bf2f(oa[row * 384 + 256 + col]);
  }
  // ---- reference points ----
  if (tid < QPB * LEVELS * 2) {
    int r = tid / (LEVELS * 2);
    int rem = tid % (LEVELS * 2);
    int q = min(q0 + r, LQ - 1);
    ref_s[r][rem / 2][rem % 2] =
        refpts[((size_t)b * LQ + q) * (LEVELS * 2) + rem];
  }
  __syncthreads();

  // ---- softmax over 16 per (query, head) ----
  if (tid < QPB * HEADS) {
    int r = tid / HEADS, h = tid % HEADS;
    float* a = &attn_s[r][h * 16];
    float m = a[0];
#pragma unroll
    for (int i = 1; i < 16; ++i) m = fmaxf(m, a[i]);
    float e[16];
    float s = 0.f;
#pragma unroll
    for (int i = 0; i < 16; ++i) {
      e[i] = __expf(a[i] - m);
      s += e[i];
    }
    float inv = 1.f / s;
#pragma unroll
    for (int i = 0; i < 16; ++i) a[i] = e[i] * inv;
  }
  __syncthreads();

  // ---- meta precompute (clamped corner idx4 + premultiplied weights) ----
  {
    float other[QPB];
#pragma unroll
    for (int r = 0; r < QPB; ++r) other[r] = __shfl_xor(accOff[r], 1, 64);

    const int s = tid >> 1;  // sample 0..127 == h*16 + l*4 + p
    const int isOdd = tid & 1;
    const int l = (s >> 2) & 3;
    const int W = (l == 0) ? 100 : (l == 1) ? 50 : (l == 2) ? 25 : 13;
    const int base = (l == 0) ? 0 : (l == 1) ? 10000 : (l == 2) ? 12500 : 13125;
    const float fW = (float)W;
    const int posx = s ^ ((s >> 4) & 7);  // bank swizzle, involution

#pragma unroll
    for (int rr = 0; rr < 4; ++rr) {
      int r = isOdd ? (4 + rr) : rr;
      float ox = isOdd ? other[r] : accOff[r];
      float oy = isOdd ? accOff[r] : other[r];
      float rx = ref_s[r][l][0];
      float ry = ref_s[r][l][1];
      float aw = attn_s[r][s];
      float x = fmaf(rx, fW, ox) - 0.5f;
      float y = fmaf(ry, fW, oy) - 0.5f;  // H == W for all levels
      float x0f = floorf(x), y0f = floorf(y);
      float lw = x - x0f, lh = y - y0f;
      int x0 = (int)x0f, y0 = (int)y0f;
      int x1 = x0 + 1, y1 = y0 + 1;
      bool x0v = (x0 >= 0) && (x0 < W);
      bool x1v = (x1 >= 0) && (x1 < W);
      bool y0v = (y0 >= 0) && (y0 < W);
      bool y1v = (y1 >= 0) && (y1 < W);
      int xc0 = min(max(x0, 0), W - 1), xc1 = min(max(x1, 0), W - 1);
      int yc0 = min(max(y0, 0), W - 1), yc1 = min(max(y1, 0), W - 1);
      float w00 = (1.f - lh) * (1.f - lw) * aw;
      float w01 = (1.f - lh) * lw * aw;
      float w10 = lh * (1.f - lw) * aw;
      float w11 = lh * lw * aw;
      meta_w[r][posx] =
          make_float4((x0v && y0v) ? w00 : 0.f, (x1v && y0v) ? w01 : 0.f,
                      (x0v && y1v) ? w10 : 0.f, (x1v && y1v) ? w11 : 0.f);
      meta_idx[r][posx] = make_ushort4(
          (unsigned short)(base + yc0 * W + xc0),
          (unsigned short)(base + yc0 * W + xc1),
          (unsigned short)(base + yc1 * W + xc0),
          (unsigned short)(base + yc1 * W + xc1));
    }
  }
  __syncthreads();

  // ---- gather: thread = (wave r, head h, dim-quad t) ----
  {
    const int ry = tid >> 6;       // 0..3 (wave id)
    const int h = (tid >> 3) & 7;  // head
    const int t = tid & 7;         // dim quad
    const float* vb = v + (size_t)b * LV_TOTAL * EMBED + h * HEAD_DIM + t * 4;

#pragma unroll
    for (int qi = 0; qi < 2; ++qi) {
      const int r = ry + qi * 4;
      float ax = 0.f, ay = 0.f, az = 0.f, aw_ = 0.f;
#pragma unroll
      for (int ss = 0; ss < 16; ++ss) {
        int pos = (h * 16 + ss) ^ h;  // same swizzle as writer
        ushort4 i4 = meta_idx[r][pos];
        float4 w4 = meta_w[r][pos];
        float4 v0 = *(const float4*)(vb + ((int)i4.x << 8));
        float4 v1 = *(const float4*)(vb + ((int)i4.y << 8));
        float4 v2 = *(const float4*)(vb + ((int)i4.z << 8));
        float4 v3 = *(const float4*)(vb + ((int)i4.w << 8));
        ax += w4.x * v0.x + w4.y * v1.x + w4.z * v2.x + w4.w * v3.x;
        ay += w4.x * v0.y + w4.y * v1.y + w4.z * v2.y + w4.w * v3.y;
        az += w4.x * v0.z + w4.y * v1.z + w4.z * v2.z + w4.w * v3.z;
        aw_ += w4.x * v0.w + w4.y * v1.w + w4.z * v2.w + w4.w * v3.w;
      }
      const int q = q0 + r;
      if (q < LQ) {
        uint2 pk;
        pk.x = (unsigned int)f2bf(ax) | ((unsigned int)f2bf(ay) << 16);
        pk.y = (unsigned int)f2bf(az) | ((unsigned int)f2bf(aw_) << 16);
        *(uint2*)(o_out + ((size_t)b * LQ + q) * EMBED + h * HEAD_DIM + t * 4) =
            pk;
      }
    }
  }
}

// ---------------------------------------------------------------------------
extern "C" void kernel_launch(void* const* d_in, const int* in_sizes, int n_in,
                              void* d_out, int out_size, void* d_ws,
                              size_t ws_size, hipStream_t stream) {
  const float* query = (const float*)d_in[0];
  const float* refpts = (const float*)d_in[1];
  const float* value = (const float*)d_in[2];
  const uint8_t* mask = (const uint8_t*)d_in[3];
  // d_in[4] = spatial_shapes (hardcoded: {100,100},{50,50},{25,25},{13,13})
  const float* W_off = (const float*)d_in[5];
  const float* b_off = (const float*)d_in[6];
  const float* W_attn = (const float*)d_in[7];
  const float* b_attn = (const float*)d_in[8];
  const float* W_val = (const float*)d_in[9];
  const float* b_val = (const float*)d_in[10];
  const float* W_out = (const float*)d_in[11];
  const float* b_out = (const float*)d_in[12];
  float* out = (float*)d_out;

  // ws layout (bytes)
  char* ws = (char*)d_ws;
  float* v_ws = (float*)ws;                       // f32 [26588][256] = 27,226,112
  unsigned short* oa_ws =
      (unsigned short*)(ws + 27226112);           // bf16 [26588][384] = 20,419,584
  unsigned short* o_ws =
      (unsigned short*)(ws + 27226112 + 20419584);  // bf16 [26588][256] = 13,613,056
  unsigned short* wt_val =
      (unsigned short*)(ws + 27226112 + 20419584 + 13613056);  // 131072
  unsigned short* wt_oa = wt_val + 256 * 256;                  // 196608
  unsigned short* wt_out = wt_oa + 384 * 256;                  // 131072

  prep_wt_kernel<<<896, 256, 0, stream>>>(W_val, W_off, W_attn, W_out, wt_val,
                                          wt_oa, wt_out);

  const int RB = (M_ROWS + 31) / 32;  // 831 row-blocks
  // v = value @ W_val + b_val, masked  (f32 out)
  gemm_rowblock_kernel<4, false, false, true, false>
      <<<RB, 256, 0, stream>>>(value, wt_val, b_val, nullptr, mask, v_ws,
                               M_ROWS);
  // [off|attn] = query @ [W_off|W_attn] + [b_off|b_attn]  (bf16 out)
  gemm_rowblock_kernel<6, false, true, false, true>
      <<<RB, 384, 0, stream>>>(query, wt_oa, b_off, b_attn, nullptr, oa_ws,
                               M_ROWS);

  dim3 g2((LQ + QPB - 1) / QPB, BS);
  gather_kernel<<<g2, 256, 0, stream>>>(refpts, v_ws, oa_ws, o_ws);

  // out = o @ W_out + b_out  (f32 out)
  gemm_rowblock_kernel<4, true, false, false, false>
      <<<RB, 256, 0, stream>>>(o_ws, wt_out, b_out, nullptr, nullptr, out,
                               M_ROWS);
}

// Round 5
// 162.454 us; speedup vs baseline: 5.1238x; 1.4180x over previous
//
#include <hip/hip_runtime.h>
#include <hip/hip_bf16.h>
#include <hip/hip_fp16.h>
#include <stdint.h>

#define EMBED 256
#define HEADS 8
#define LEVELS 4
#define POINTS 4
#define HEAD_DIM 32
#define BS 2
#define LV_TOTAL 13294
#define LQ LV_TOTAL
#define TP 128 /* HEADS*LEVELS*POINTS */
#define M_ROWS (BS * LV_TOTAL) /* 26588 */
#define QPB 8

typedef __attribute__((ext_vector_type(8))) short bf16x8;
typedef __attribute__((ext_vector_type(4))) float f32x4;

static __device__ __forceinline__ unsigned short f2bf(float x) {
  __hip_bfloat16 h = __float2bfloat16(x);
  return *reinterpret_cast<unsigned short*>(&h);
}
static __device__ __forceinline__ float bf2f(unsigned short u) {
  return __uint_as_float(((unsigned int)u) << 16);
}
static __device__ __forceinline__ unsigned short f2hbits(float x) {
  __half h = __float2half(x);
  return *reinterpret_cast<unsigned short*>(&h);
}
static __device__ __forceinline__ float hbits2f(unsigned short u) {
  __half h = *reinterpret_cast<__half*>(&u);
  return __half2float(h);
}

// ---------------------------------------------------------------------------
// prep_wt: transpose + convert all weight matrices to bf16 WT[n][k] layout.
// blocks: [0,256) W_val | [256,512) W_off | [512,640) W_attn | [640,896) W_out
// ---------------------------------------------------------------------------
__global__ __launch_bounds__(256) void prep_wt_kernel(
    const float* __restrict__ W_val, const float* __restrict__ W_off,
    const float* __restrict__ W_attn, const float* __restrict__ W_out,
    unsigned short* __restrict__ WT_val, unsigned short* __restrict__ WT_oa,
    unsigned short* __restrict__ WT_out) {
  const int bid = blockIdx.x;
  const int k = threadIdx.x;  // 0..255
  const float* src;
  unsigned short* dst;
  int n, N_src;
  if (bid < 256) {
    src = W_val; dst = WT_val; n = bid; N_src = 256;
  } else if (bid < 512) {
    src = W_off; dst = WT_oa; n = bid - 256; N_src = 256;
  } else if (bid < 640) {
    src = W_attn; dst = WT_oa + 256 * 256; n = bid - 512; N_src = 128;
  } else {
    src = W_out; dst = WT_out; n = bid - 640; N_src = 256;
  }
  dst[n * 256 + k] = f2bf(src[(size_t)k * N_src + n]);
}

// ---------------------------------------------------------------------------
// LDS-B MFMA GEMM: C(M x NTOT) = A(M x 256) @ B(256 x NTOT) + bias.
// grid = (ceil(M/64), NTOT/64). Block = 256 thr = 4 waves; the block's 64-col
// B panel (64 x 256 bf16 = 32 KB) is staged to LDS once with XOR swizzle
// (byte ^= (col&7)<<4, G4 pattern); each wave then computes 16 rows x 64 cols
// with per-kk {1 A-frag global load, 4 swizzled ds_read_b128, 4 MFMA}.
// OUT_MODE: 0 = f32 [row][NTOT], 1 = bf16 [row][NTOT],
//           2 = f16 head-major vh[col>>5][row][col&31].
// ---------------------------------------------------------------------------
template <int NTOT, bool A_BF16, int OUT_MODE, bool MASKED, bool SPLIT_BIAS>
__global__ __launch_bounds__(256) void gemm_ldsb_kernel(
    const void* __restrict__ Av, const unsigned short* __restrict__ BT,
    const float* __restrict__ bias0, const float* __restrict__ bias1,
    const uint8_t* __restrict__ mask, void* __restrict__ Cv, int M) {
  __shared__ uint4 bpanel4[2048];  // 32 KB swizzled B panel
  unsigned short* bpanel = (unsigned short*)bpanel4;
  const int tid = threadIdx.x;
  const int col0 = blockIdx.y * 64;

  // ---- stage B panel (64 cols x 256 k, bf16), XOR-swizzled ----
#pragma unroll
  for (int it = 0; it < 8; ++it) {
    int c = it * 256 + tid;  // chunk id 0..2047 (16B chunks)
    int col = c >> 5;        // 0..63
    int kc = c & 31;         // 16B chunk within the col's 512B row
    uint4 vdat = *(const uint4*)(BT + ((size_t)(col0 + col)) * 256 + kc * 8);
    int byteoff = (col << 9) + ((kc << 4) ^ ((col & 7) << 4));
    *(uint4*)((char*)bpanel + byteoff) = vdat;
  }
  __syncthreads();

  const int wave = tid >> 6;
  const int lane = tid & 63;
  const int lr = lane & 15;
  const int kq = lane >> 4;  // 0..3
  const int rowW = blockIdx.x * 64 + wave * 16;
  const int arow = min(rowW + lr, M - 1);

  f32x4 acc[4];
#pragma unroll
  for (int c = 0; c < 4; ++c) acc[c] = (f32x4){0.f, 0.f, 0.f, 0.f};

  const float* Af = (const float*)Av;
  const unsigned short* Ab = (const unsigned short*)Av;

#pragma unroll
  for (int kk = 0; kk < 8; ++kk) {
    const int k0 = kk * 32 + kq * 8;
    bf16x8 a;
    if constexpr (A_BF16) {
      a = *(const bf16x8*)(Ab + (size_t)arow * 256 + k0);
    } else {
      float4 p0 = *(const float4*)(Af + (size_t)arow * 256 + k0);
      float4 p1 = *(const float4*)(Af + (size_t)arow * 256 + k0 + 4);
      a[0] = (short)f2bf(p0.x); a[1] = (short)f2bf(p0.y);
      a[2] = (short)f2bf(p0.z); a[3] = (short)f2bf(p0.w);
      a[4] = (short)f2bf(p1.x); a[5] = (short)f2bf(p1.y);
      a[6] = (short)f2bf(p1.z); a[7] = (short)f2bf(p1.w);
    }
#pragma unroll
    for (int c = 0; c < 4; ++c) {
      const int col = c * 16 + lr;
      const int byteoff = (col << 9) + (((k0 * 2)) ^ ((col & 7) << 4));
      bf16x8 bfrag = *(const bf16x8*)((const char*)bpanel + byteoff);
      acc[c] =
          __builtin_amdgcn_mfma_f32_16x16x32_bf16(a, bfrag, acc[c], 0, 0, 0);
    }
  }

  // epilogue: D col = lane&15, row = (lane>>4)*4 + i   [m89-verified]
#pragma unroll
  for (int c = 0; c < 4; ++c) {
    const int col = col0 + c * 16 + lr;
    float bv;
    if constexpr (SPLIT_BIAS)
      bv = (col < 256) ? bias0[col] : bias1[col - 256];
    else
      bv = bias0[col];
#pragma unroll
    for (int i = 0; i < 4; ++i) {
      const int row = rowW + kq * 4 + i;
      if (row < M) {
        float o = acc[c][i] + bv;
        if constexpr (MASKED) {
          if (mask[row]) o = 0.f;
        }
        if constexpr (OUT_MODE == 0) {
          ((float*)Cv)[(size_t)row * NTOT + col] = o;
        } else if constexpr (OUT_MODE == 1) {
          ((unsigned short*)Cv)[(size_t)row * NTOT + col] = f2bf(o);
        } else {
          // f16 head-major: vh[h][row][d]
          ((unsigned short*)Cv)[(size_t)(col >> 5) * ((size_t)M * 32) +
                                (size_t)row * 32 + (col & 31)] = f2hbits(o);
        }
      }
    }
  }
}

// ---------------------------------------------------------------------------
// gather_kernel: per block QPB(8) queries of one batch, 256 threads.
// v is f16 head-major vh[h][b*LV+lv][32].  Phases 1-4 (oa load / softmax /
// meta precompute) as round 4; meta_w packed f16.  Gather phase: thread =
// (q = wave*2 + lane>>5, h = (lane>>2)&7, t = lane&3) owning 8 dims; per
// sample: 2 LDS broadcast reads + 4 x uint4 (16B) corner loads + 32 FMA.
// ---------------------------------------------------------------------------
__global__ __launch_bounds__(256) void gather_kernel(
    const float* __restrict__ refpts,
    const __half* __restrict__ vh,          // f16 head-major
    const unsigned short* __restrict__ oa,  // bf16 (BS*LQ, 384) [off|attn]
    unsigned short* __restrict__ o_out) {   // bf16 (BS*LQ, 256)
  __shared__ float attn_s[QPB][TP];          // 4 KB
  __shared__ float ref_s[QPB][LEVELS][2];
  __shared__ ushort4 meta_idx[QPB][TP];      // 8 KB
  __shared__ ushort4 meta_w[QPB][TP];        // 8 KB (f16 bits)

  const int b = blockIdx.y;
  const int q0 = blockIdx.x * QPB;
  const int tid = threadIdx.x;

  // ---- load offsets (col = tid, one per query, stays in registers) ----
  float accOff[QPB];
#pragma unroll
  for (int r = 0; r < QPB; ++r) {
    int q = min(q0 + r, LQ - 1);
    size_t row = (size_t)b * LQ + q;
    accOff[r] = bf2f(oa[row * 384 + tid]);
  }
  // ---- load attn logits to LDS ----
#pragma unroll
  for (int i = 0; i < 4; ++i) {
    int idx = i * 256 + tid;  // 0..1023
    int r = idx >> 7, col = idx & 127;
    int q = min(q0 + r, LQ - 1);
    size_t row = (size_t)b * LQ + q;
    attn_s[r][col] = bf2f(oa[row * 384 + 256 + col]);
  }
  // ---- reference points ----
  if (tid < QPB * LEVELS * 2) {
    int r = tid / (LEVELS * 2);
    int rem = tid % (LEVELS * 2);
    int q = min(q0 + r, LQ - 1);
    ref_s[r][rem / 2][rem % 2] =
        refpts[((size_t)b * LQ + q) * (LEVELS * 2) + rem];
  }
  __syncthreads();

  // ---- softmax over 16 per (query, head) ----
  if (tid < QPB * HEADS) {
    int r = tid / HEADS, h = tid % HEADS;
    float* a = &attn_s[r][h * 16];
    float m = a[0];
#pragma unroll
    for (int i = 1; i < 16; ++i) m = fmaxf(m, a[i]);
    float e[16];
    float s = 0.f;
#pragma unroll
    for (int i = 0; i < 16; ++i) {
      e[i] = __expf(a[i] - m);
      s += e[i];
    }
    float inv = 1.f / s;
#pragma unroll
    for (int i = 0; i < 16; ++i) a[i] = e[i] * inv;
  }
  __syncthreads();

  // ---- meta precompute (clamped corner idx4 + premultiplied f16 weights) ----
  {
    float other[QPB];
#pragma unroll
    for (int r = 0; r < QPB; ++r) other[r] = __shfl_xor(accOff[r], 1, 64);

    const int s = tid >> 1;  // sample 0..127 == h*16 + l*4 + p
    const int isOdd = tid & 1;
    const int l = (s >> 2) & 3;
    const int W = (l == 0) ? 100 : (l == 1) ? 50 : (l == 2) ? 25 : 13;
    const int base = (l == 0) ? 0 : (l == 1) ? 10000 : (l == 2) ? 12500 : 13125;
    const float fW = (float)W;
    const int posx = s ^ ((s >> 4) & 7);  // bank swizzle, involution

#pragma unroll
    for (int rr = 0; rr < 4; ++rr) {
      int r = isOdd ? (4 + rr) : rr;
      float ox = isOdd ? other[r] : accOff[r];
      float oy = isOdd ? accOff[r] : other[r];
      float rx = ref_s[r][l][0];
      float ry = ref_s[r][l][1];
      float aw = attn_s[r][s];
      float x = fmaf(rx, fW, ox) - 0.5f;
      float y = fmaf(ry, fW, oy) - 0.5f;  // H == W for all levels
      float x0f = floorf(x), y0f = floorf(y);
      float lw = x - x0f, lh = y - y0f;
      int x0 = (int)x0f, y0 = (int)y0f;
      int x1 = x0 + 1, y1 = y0 + 1;
      bool x0v = (x0 >= 0) && (x0 < W);
      bool x1v = (x1 >= 0) && (x1 < W);
      bool y0v = (y0 >= 0) && (y0 < W);
      bool y1v = (y1 >= 0) && (y1 < W);
      int xc0 = min(max(x0, 0), W - 1), xc1 = min(max(x1, 0), W - 1);
      int yc0 = min(max(y0, 0), W - 1), yc1 = min(max(y1, 0), W - 1);
      float w00 = (1.f - lh) * (1.f - lw) * aw;
      float w01 = (1.f - lh) * lw * aw;
      float w10 = lh * (1.f - lw) * aw;
      float w11 = lh * lw * aw;
      meta_w[r][posx] = make_ushort4(
          f2hbits((x0v && y0v) ? w00 : 0.f), f2hbits((x1v && y0v) ? w01 : 0.f),
          f2hbits((x0v && y1v) ? w10 : 0.f), f2hbits((x1v && y1v) ? w11 : 0.f));
      meta_idx[r][posx] = make_ushort4(
          (unsigned short)(yc0 * W + xc0 + base),
          (unsigned short)(yc0 * W + xc1 + base),
          (unsigned short)(yc1 * W + xc0 + base),
          (unsigned short)(yc1 * W + xc1 + base));
    }
  }
  __syncthreads();

  // ---- gather: thread = (q = wave*2 + lane>>5, h, t dim-octet) ----
  {
    const int lane = tid & 63;
    const int q = (tid >> 6) * 2 + (lane >> 5);  // 0..7
    const int h = (lane >> 2) & 7;               // head
    const int t = lane & 3;                      // dim octet (8 dims)
    const __half* vb = vh + (size_t)h * ((size_t)M_ROWS * 32) +
                       (size_t)b * LV_TOTAL * 32 + t * 8;

    float acc[8];
#pragma unroll
    for (int j = 0; j < 8; ++j) acc[j] = 0.f;

#pragma unroll
    for (int ss = 0; ss < 16; ++ss) {
      const int pos = (h * 16 + ss) ^ h;  // same swizzle as writer
      const ushort4 i4 = meta_idx[q][pos];
      const ushort4 wb = meta_w[q][pos];
      const float w0 = hbits2f(wb.x), w1 = hbits2f(wb.y);
      const float w2 = hbits2f(wb.z), w3 = hbits2f(wb.w);
      const uint4 c0 = *(const uint4*)(vb + (size_t)i4.x * 32);
      const uint4 c1 = *(const uint4*)(vb + (size_t)i4.y * 32);
      const uint4 c2 = *(const uint4*)(vb + (size_t)i4.z * 32);
      const uint4 c3 = *(const uint4*)(vb + (size_t)i4.w * 32);
      const __half2* h0 = (const __half2*)&c0;
      const __half2* h1 = (const __half2*)&c1;
      const __half2* h2 = (const __half2*)&c2;
      const __half2* h3 = (const __half2*)&c3;
#pragma unroll
      for (int j = 0; j < 4; ++j) {
        float2 f0 = __half22float2(h0[j]);
        float2 f1 = __half22float2(h1[j]);
        float2 f2 = __half22float2(h2[j]);
        float2 f3 = __half22float2(h3[j]);
        acc[j * 2] = fmaf(f0.x, w0, acc[j * 2]);
        acc[j * 2 + 1] = fmaf(f0.y, w0, acc[j * 2 + 1]);
        acc[j * 2] = fmaf(f1.x, w1, acc[j * 2]);
        acc[j * 2 + 1] = fmaf(f1.y, w1, acc[j * 2 + 1]);
        acc[j * 2] = fmaf(f2.x, w2, acc[j * 2]);
        acc[j * 2 + 1] = fmaf(f2.y, w2, acc[j * 2 + 1]);
        acc[j * 2] = fmaf(f3.x, w3, acc[j * 2]);
        acc[j * 2 + 1] = fmaf(f3.y, w3, acc[j * 2 + 1]);
      }
    }

    const int qg = q0 + q;
    if (qg < LQ) {
      uint4 pk;
      pk.x = (unsigned int)f2bf(acc[0]) | ((unsigned int)f2bf(acc[1]) << 16);
      pk.y = (unsigned int)f2bf(acc[2]) | ((unsigned int)f2bf(acc[3]) << 16);
      pk.z = (unsigned int)f2bf(acc[4]) | ((unsigned int)f2bf(acc[5]) << 16);
      pk.w = (unsigned int)f2bf(acc[6]) | ((unsigned int)f2bf(acc[7]) << 16);
      *(uint4*)(o_out + ((size_t)b * LQ + qg) * EMBED + h * HEAD_DIM + t * 8) =
          pk;
    }
  }
}

// ---------------------------------------------------------------------------
extern "C" void kernel_launch(void* const* d_in, const int* in_sizes, int n_in,
                              void* d_out, int out_size, void* d_ws,
                              size_t ws_size, hipStream_t stream) {
  const float* query = (const float*)d_in[0];
  const float* refpts = (const float*)d_in[1];
  const float* value = (const float*)d_in[2];
  const uint8_t* mask = (const uint8_t*)d_in[3];
  // d_in[4] = spatial_shapes (hardcoded: {100,100},{50,50},{25,25},{13,13})
  const float* W_off = (const float*)d_in[5];
  const float* b_off = (const float*)d_in[6];
  const float* W_attn = (const float*)d_in[7];
  const float* b_attn = (const float*)d_in[8];
  const float* W_val = (const float*)d_in[9];
  const float* b_val = (const float*)d_in[10];
  const float* W_out = (const float*)d_in[11];
  const float* b_out = (const float*)d_in[12];
  float* out = (float*)d_out;

  // ws layout (bytes)
  char* ws = (char*)d_ws;
  __half* vh_ws = (__half*)ws;  // f16 head-major [8][26588][32] = 13,613,056
  unsigned short* oa_ws =
      (unsigned short*)(ws + 13613056);  // bf16 [26588][384] = 20,419,584
  unsigned short* o_ws =
      (unsigned short*)(ws + 13613056 + 20419584);  // bf16 [26588][256]
  unsigned short* wt_val =
      (unsigned short*)(ws + 13613056 + 20419584 + 13613056);  // 131072 B
  unsigned short* wt_oa = wt_val + 256 * 256;                  // 196608 B
  unsigned short* wt_out = wt_oa + 384 * 256;                  // 131072 B

  prep_wt_kernel<<<896, 256, 0, stream>>>(W_val, W_off, W_attn, W_out, wt_val,
                                          wt_oa, wt_out);

  const int RB = (M_ROWS + 63) / 64;  // 416 row blocks
  // v = value @ W_val + b_val, masked -> f16 head-major
  gemm_ldsb_kernel<256, false, 2, true, false>
      <<<dim3(RB, 4), 256, 0, stream>>>(value, wt_val, b_val, nullptr, mask,
                                        vh_ws, M_ROWS);
  // [off|attn] = query @ [W_off|W_attn] + biases -> bf16
  gemm_ldsb_kernel<384, false, 1, false, true>
      <<<dim3(RB, 6), 256, 0, stream>>>(query, wt_oa, b_off, b_attn, nullptr,
                                        oa_ws, M_ROWS);

  dim3 g2((LQ + QPB - 1) / QPB, BS);
  gather_kernel<<<g2, 256, 0, stream>>>(refpts, vh_ws, oa_ws, o_ws);

  // out = o @ W_out + b_out -> f32
  gemm_ldsb_kernel<256, true, 0, false, false>
      <<<dim3(RB, 4), 256, 0, stream>>>(o_ws, wt_out, b_out, nullptr, nullptr,
                                        out, M_ROWS);
}

// Round 6
// 148.775 us; speedup vs baseline: 5.5950x; 1.0919x over previous
//
#include <hip/hip_runtime.h>
#include <hip/hip_bf16.h>
#include <hip/hip_fp16.h>
#include <stdint.h>

#define EMBED 256
#define HEADS 8
#define LEVELS 4
#define POINTS 4
#define HEAD_DIM 32
#define BS 2
#define LV_TOTAL 13294
#define LQ LV_TOTAL
#define TP 128 /* HEADS*LEVELS*POINTS */
#define M_ROWS (BS * LV_TOTAL) /* 26588 */
#define QPB 8

typedef __attribute__((ext_vector_type(8))) short bf16x8;
typedef __attribute__((ext_vector_type(4))) float f32x4;

static __device__ __forceinline__ unsigned short f2bf(float x) {
  __hip_bfloat16 h = __float2bfloat16(x);
  return *reinterpret_cast<unsigned short*>(&h);
}
static __device__ __forceinline__ float bf2f(unsigned short u) {
  return __uint_as_float(((unsigned int)u) << 16);
}
static __device__ __forceinline__ unsigned short f2hbits(float x) {
  __half h = __float2half(x);
  return *reinterpret_cast<unsigned short*>(&h);
}

// v_fma_mix_f32: acc(f32) += f16(sel vs of pk) * f16(sel ws of w)
#define MIX(acc, pk, w, vs, ws)                                          \
  asm("v_fma_mix_f32 %0, %1, %2, %0 op_sel:[" #vs "," #ws                \
      ",0] op_sel_hi:[1,1,0]"                                            \
      : "+v"(acc)                                                        \
      : "v"(pk), "v"(w))

// one bilinear corner: 8 dims (4 packed half2) scaled by f16 weight (half ws)
#define CORNER(cv, wreg, ws)                                             \
  MIX(acc[0], cv.x, wreg, 0, ws); MIX(acc[1], cv.x, wreg, 1, ws);        \
  MIX(acc[2], cv.y, wreg, 0, ws); MIX(acc[3], cv.y, wreg, 1, ws);        \
  MIX(acc[4], cv.z, wreg, 0, ws); MIX(acc[5], cv.z, wreg, 1, ws);        \
  MIX(acc[6], cv.w, wreg, 0, ws); MIX(acc[7], cv.w, wreg, 1, ws)

// ---------------------------------------------------------------------------
// prep_wt: transpose + convert all weight matrices to bf16 WT[n][k] layout.
// ---------------------------------------------------------------------------
__global__ __launch_bounds__(256) void prep_wt_kernel(
    const float* __restrict__ W_val, const float* __restrict__ W_off,
    const float* __restrict__ W_attn, const float* __restrict__ W_out,
    unsigned short* __restrict__ WT_val, unsigned short* __restrict__ WT_oa,
    unsigned short* __restrict__ WT_out) {
  const int bid = blockIdx.x;
  const int k = threadIdx.x;  // 0..255
  const float* src;
  unsigned short* dst;
  int n, N_src;
  if (bid < 256) {
    src = W_val; dst = WT_val; n = bid; N_src = 256;
  } else if (bid < 512) {
    src = W_off; dst = WT_oa; n = bid - 256; N_src = 256;
  } else if (bid < 640) {
    src = W_attn; dst = WT_oa + 256 * 256; n = bid - 512; N_src = 128;
  } else {
    src = W_out; dst = WT_out; n = bid - 640; N_src = 256;
  }
  dst[n * 256 + k] = f2bf(src[(size_t)k * N_src + n]);
}

// ---------------------------------------------------------------------------
// Shared GEMM body: C(M x NTOT) = A(M x 256) @ B(256 x NTOT) + bias, one
// 64-col strip per block. B panel (64x256 bf16, 32 KB) staged to LDS with
// XOR swizzle; 4 waves x {16 rows, 64 cols}; per kk: 1 A-frag, 4 ds_read_b128,
// 4 MFMA.  OUT_MODE: 0=f32, 1=bf16, 2=f16 head-major vh[col>>5][row][col&31].
// ---------------------------------------------------------------------------
template <int NTOT, bool A_BF16, int OUT_MODE, bool MASKED, bool SPLIT_BIAS>
static __device__ __forceinline__ void gemm_body(
    unsigned short* bpanel, const void* __restrict__ Av,
    const unsigned short* __restrict__ BT, const float* __restrict__ bias0,
    const float* __restrict__ bias1, const uint8_t* __restrict__ mask,
    void* __restrict__ Cv, int M, int strip) {
  const int tid = threadIdx.x;
  const int col0 = strip * 64;

  // ---- stage B panel (64 cols x 256 k, bf16), XOR-swizzled ----
#pragma unroll
  for (int it = 0; it < 8; ++it) {
    int c = it * 256 + tid;  // chunk id 0..2047 (16B chunks)
    int col = c >> 5;        // 0..63
    int kc = c & 31;         // 16B chunk within the col's 512B row
    uint4 vdat = *(const uint4*)(BT + ((size_t)(col0 + col)) * 256 + kc * 8);
    int byteoff = (col << 9) + ((kc << 4) ^ ((col & 7) << 4));
    *(uint4*)((char*)bpanel + byteoff) = vdat;
  }
  __syncthreads();

  const int wave = tid >> 6;
  const int lane = tid & 63;
  const int lr = lane & 15;
  const int kq = lane >> 4;  // 0..3
  const int rowW = blockIdx.x * 64 + wave * 16;
  const int arow = min(rowW + lr, M - 1);

  f32x4 acc[4];
#pragma unroll
  for (int c = 0; c < 4; ++c) acc[c] = (f32x4){0.f, 0.f, 0.f, 0.f};

  const float* Af = (const float*)Av;
  const unsigned short* Ab = (const unsigned short*)Av;

#pragma unroll
  for (int kk = 0; kk < 8; ++kk) {
    const int k0 = kk * 32 + kq * 8;
    bf16x8 a;
    if constexpr (A_BF16) {
      a = *(const bf16x8*)(Ab + (size_t)arow * 256 + k0);
    } else {
      float4 p0 = *(const float4*)(Af + (size_t)arow * 256 + k0);
      float4 p1 = *(const float4*)(Af + (size_t)arow * 256 + k0 + 4);
      a[0] = (short)f2bf(p0.x); a[1] = (short)f2bf(p0.y);
      a[2] = (short)f2bf(p0.z); a[3] = (short)f2bf(p0.w);
      a[4] = (short)f2bf(p1.x); a[5] = (short)f2bf(p1.y);
      a[6] = (short)f2bf(p1.z); a[7] = (short)f2bf(p1.w);
    }
#pragma unroll
    for (int c = 0; c < 4; ++c) {
      const int col = c * 16 + lr;
      const int byteoff = (col << 9) + (((k0 * 2)) ^ ((col & 7) << 4));
      bf16x8 bfrag = *(const bf16x8*)((const char*)bpanel + byteoff);
      acc[c] =
          __builtin_amdgcn_mfma_f32_16x16x32_bf16(a, bfrag, acc[c], 0, 0, 0);
    }
  }

  // epilogue: D col = lane&15, row = (lane>>4)*4 + i   [m89-verified]
#pragma unroll
  for (int c = 0; c < 4; ++c) {
    const int col = col0 + c * 16 + lr;
    float bv;
    if constexpr (SPLIT_BIAS)
      bv = (col < 256) ? bias0[col] : bias1[col - 256];
    else
      bv = bias0[col];
#pragma unroll
    for (int i = 0; i < 4; ++i) {
      const int row = rowW + kq * 4 + i;
      if (row < M) {
        float o = acc[c][i] + bv;
        if constexpr (MASKED) {
          if (mask[row]) o = 0.f;
        }
        if constexpr (OUT_MODE == 0) {
          ((float*)Cv)[(size_t)row * NTOT + col] = o;
        } else if constexpr (OUT_MODE == 1) {
          ((unsigned short*)Cv)[(size_t)row * NTOT + col] = f2bf(o);
        } else {
          ((unsigned short*)Cv)[(size_t)(col >> 5) * ((size_t)M * 32) +
                                (size_t)row * 32 + (col & 31)] = f2hbits(o);
        }
      }
    }
  }
}

// fat kernel: strips 0-3 = vproj (value -> f16 head-major vh),
//             strips 4-9 = oa (query -> bf16 [off|attn])
__global__ __launch_bounds__(256) void gemm_fused01_kernel(
    const float* __restrict__ value, const float* __restrict__ query,
    const unsigned short* __restrict__ wt_val,
    const unsigned short* __restrict__ wt_oa, const float* __restrict__ b_val,
    const float* __restrict__ b_off, const float* __restrict__ b_attn,
    const uint8_t* __restrict__ mask, unsigned short* __restrict__ vh,
    unsigned short* __restrict__ oa, int M) {
  __shared__ uint4 bpanel4[2048];  // 32 KB
  unsigned short* bp = (unsigned short*)bpanel4;
  if (blockIdx.y < 4)
    gemm_body<256, false, 2, true, false>(bp, value, wt_val, b_val, nullptr,
                                          mask, vh, M, blockIdx.y);
  else
    gemm_body<384, false, 1, false, true>(bp, query, wt_oa, b_off, b_attn,
                                          nullptr, oa, M, blockIdx.y - 4);
}

__global__ __launch_bounds__(256) void gemm_out_kernel(
    const unsigned short* __restrict__ o_in,
    const unsigned short* __restrict__ wt_out, const float* __restrict__ b_out,
    float* __restrict__ out, int M) {
  __shared__ uint4 bpanel4[2048];
  unsigned short* bp = (unsigned short*)bpanel4;
  gemm_body<256, true, 0, false, false>(bp, o_in, wt_out, b_out, nullptr,
                                        nullptr, out, M, blockIdx.y);
}

// ---------------------------------------------------------------------------
// query remap: level-0 blocks (bid<1250) cover a 2-row x 4-col spatial patch
// of the 100x100 level-0 raster (bijective); later blocks stay linear.
// ---------------------------------------------------------------------------
static __device__ __forceinline__ int qmap_of(int bid, int r) {
  if (bid < 1250) {
    int ty = bid / 25, tx = bid - ty * 25;
    return (ty * 2 + (r >> 2)) * 100 + tx * 4 + (r & 3);
  }
  return bid * 8 + r;
}

// ---------------------------------------------------------------------------
// gather_kernel: per block QPB(8) queries of one batch, 256 threads.
// v is f16 head-major vh[h][b*LV+lv][32].  Gather inner loop uses
// v_fma_mix_f32 (f16*f16+f32, zero converts) + 32-bit offset addressing.
// ---------------------------------------------------------------------------
__global__ __launch_bounds__(256) void gather_kernel(
    const float* __restrict__ refpts,
    const __half* __restrict__ vh,          // f16 head-major
    const unsigned short* __restrict__ oa,  // bf16 (BS*LQ, 384) [off|attn]
    unsigned short* __restrict__ o_out) {   // bf16 (BS*LQ, 256)
  __shared__ float attn_s[QPB][TP];      // 4 KB
  __shared__ float ref_s[QPB][LEVELS][2];
  __shared__ ushort4 meta_idx[QPB][TP];  // 8 KB
  __shared__ uint2 meta_w[QPB][TP];      // 8 KB (4x f16 bits)

  const int b = blockIdx.y;
  const int bid = blockIdx.x;
  const int tid = threadIdx.x;

  int qmap[QPB];
#pragma unroll
  for (int r = 0; r < QPB; ++r) qmap[r] = min(qmap_of(bid, r), LQ - 1);

  // ---- load offsets (col = tid, one per query, stays in registers) ----
  float accOff[QPB];
#pragma unroll
  for (int r = 0; r < QPB; ++r) {
    size_t row = (size_t)b * LQ + qmap[r];
    accOff[r] = bf2f(oa[row * 384 + tid]);
  }
  // ---- load attn logits to LDS ----
#pragma unroll
  for (int i = 0; i < 4; ++i) {
    int idx = i * 256 + tid;  // 0..1023
    int r = idx >> 7, col = idx & 127;
    size_t row = (size_t)b * LQ + qmap[r];
    attn_s[r][col] = bf2f(oa[row * 384 + 256 + col]);
  }
  // ---- reference points ----
  if (tid < QPB * LEVELS * 2) {
    int r = tid / (LEVELS * 2);
    int rem = tid % (LEVELS * 2);
    ref_s[r][rem / 2][rem % 2] =
        refpts[((size_t)b * LQ + qmap[r]) * (LEVELS * 2) + rem];
  }
  __syncthreads();

  // ---- softmax over 16 per (query, head) ----
  if (tid < QPB * HEADS) {
    int r = tid / HEADS, h = tid % HEADS;
    float* a = &attn_s[r][h * 16];
    float m = a[0];
#pragma unroll
    for (int i = 1; i < 16; ++i) m = fmaxf(m, a[i]);
    float e[16];
    float s = 0.f;
#pragma unroll
    for (int i = 0; i < 16; ++i) {
      e[i] = __expf(a[i] - m);
      s += e[i];
    }
    float inv = 1.f / s;
#pragma unroll
    for (int i = 0; i < 16; ++i) a[i] = e[i] * inv;
  }
  __syncthreads();

  // ---- meta precompute (clamped corner idx4 + premultiplied f16 weights) ----
  {
    float other[QPB];
#pragma unroll
    for (int r = 0; r < QPB; ++r) other[r] = __shfl_xor(accOff[r], 1, 64);

    const int s = tid >> 1;  // sample 0..127 == h*16 + l*4 + p
    const int isOdd = tid & 1;
    const int l = (s >> 2) & 3;
    const int W = (l == 0) ? 100 : (l == 1) ? 50 : (l == 2) ? 25 : 13;
    const int base = (l == 0) ? 0 : (l == 1) ? 10000 : (l == 2) ? 12500 : 13125;
    const float fW = (float)W;
    const int posx = s ^ ((s >> 4) & 7);  // bank swizzle, involution

#pragma unroll
    for (int rr = 0; rr < 4; ++rr) {
      int r = isOdd ? (4 + rr) : rr;
      float ox = isOdd ? other[r] : accOff[r];
      float oy = isOdd ? accOff[r] : other[r];
      float rx = ref_s[r][l][0];
      float ry = ref_s[r][l][1];
      float aw = attn_s[r][s];
      float x = fmaf(rx, fW, ox) - 0.5f;
      float y = fmaf(ry, fW, oy) - 0.5f;  // H == W for all levels
      float x0f = floorf(x), y0f = floorf(y);
      float lw = x - x0f, lh = y - y0f;
      int x0 = (int)x0f, y0 = (int)y0f;
      int x1 = x0 + 1, y1 = y0 + 1;
      bool x0v = (x0 >= 0) && (x0 < W);
      bool x1v = (x1 >= 0) && (x1 < W);
      bool y0v = (y0 >= 0) && (y0 < W);
      bool y1v = (y1 >= 0) && (y1 < W);
      int xc0 = min(max(x0, 0), W - 1), xc1 = min(max(x1, 0), W - 1);
      int yc0 = min(max(y0, 0), W - 1), yc1 = min(max(y1, 0), W - 1);
      float w00 = (1.f - lh) * (1.f - lw) * aw;
      float w01 = (1.f - lh) * lw * aw;
      float w10 = lh * (1.f - lw) * aw;
      float w11 = lh * lw * aw;
      unsigned int u00 = f2hbits((x0v && y0v) ? w00 : 0.f);
      unsigned int u01 = f2hbits((x1v && y0v) ? w01 : 0.f);
      unsigned int u10 = f2hbits((x0v && y1v) ? w10 : 0.f);
      unsigned int u11 = f2hbits((x1v && y1v) ? w11 : 0.f);
      meta_w[r][posx] = make_uint2(u00 | (u01 << 16), u10 | (u11 << 16));
      meta_idx[r][posx] = make_ushort4(
          (unsigned short)(yc0 * W + xc0 + base),
          (unsigned short)(yc0 * W + xc1 + base),
          (unsigned short)(yc1 * W + xc0 + base),
          (unsigned short)(yc1 * W + xc1 + base));
    }
  }
  __syncthreads();

  // ---- gather: thread = (q = wave*2 + lane>>5, h, t dim-octet) ----
  {
    const int lane = tid & 63;
    const int q = (tid >> 6) * 2 + (lane >> 5);  // 0..7
    const int h = (lane >> 2) & 7;               // head
    const int t = lane & 3;                      // dim octet (8 dims)
    // uniform base (SGPR) + 32-bit per-lane offset
    const char* vbase = (const char*)(vh + (size_t)b * LV_TOTAL * 32);
    const unsigned int laneoff =
        ((unsigned int)h * (M_ROWS * 32) + (unsigned int)t * 8) * 2u;

    float acc[8];
#pragma unroll
    for (int j = 0; j < 8; ++j) acc[j] = 0.f;

#pragma unroll
    for (int ss = 0; ss < 16; ++ss) {
      const int pos = (h * 16 + ss) ^ h;  // same swizzle as writer
      const ushort4 i4 = meta_idx[q][pos];
      const uint2 wpk = meta_w[q][pos];
      const uint4 c0 =
          *(const uint4*)(vbase + (laneoff + ((unsigned int)i4.x << 6)));
      const uint4 c1 =
          *(const uint4*)(vbase + (laneoff + ((unsigned int)i4.y << 6)));
      const uint4 c2 =
          *(const uint4*)(vbase + (laneoff + ((unsigned int)i4.z << 6)));
      const uint4 c3 =
          *(const uint4*)(vbase + (laneoff + ((unsigned int)i4.w << 6)));
      CORNER(c0, wpk.x, 0);
      CORNER(c1, wpk.x, 1);
      CORNER(c2, wpk.y, 0);
      CORNER(c3, wpk.y, 1);
    }

    const int qg = qmap[q];
    if (qmap_of(bid, q) < LQ) {
      uint4 pk;
      pk.x = (unsigned int)f2bf(acc[0]) | ((unsigned int)f2bf(acc[1]) << 16);
      pk.y = (unsigned int)f2bf(acc[2]) | ((unsigned int)f2bf(acc[3]) << 16);
      pk.z = (unsigned int)f2bf(acc[4]) | ((unsigned int)f2bf(acc[5]) << 16);
      pk.w = (unsigned int)f2bf(acc[6]) | ((unsigned int)f2bf(acc[7]) << 16);
      *(uint4*)(o_out + ((size_t)b * LQ + qg) * EMBED + h * HEAD_DIM + t * 8) =
          pk;
    }
  }
}

// ---------------------------------------------------------------------------
extern "C" void kernel_launch(void* const* d_in, const int* in_sizes, int n_in,
                              void* d_out, int out_size, void* d_ws,
                              size_t ws_size, hipStream_t stream) {
  const float* query = (const float*)d_in[0];
  const float* refpts = (const float*)d_in[1];
  const float* value = (const float*)d_in[2];
  const uint8_t* mask = (const uint8_t*)d_in[3];
  // d_in[4] = spatial_shapes (hardcoded: {100,100},{50,50},{25,25},{13,13})
  const float* W_off = (const float*)d_in[5];
  const float* b_off = (const float*)d_in[6];
  const float* W_attn = (const float*)d_in[7];
  const float* b_attn = (const float*)d_in[8];
  const float* W_val = (const float*)d_in[9];
  const float* b_val = (const float*)d_in[10];
  const float* W_out = (const float*)d_in[11];
  const float* b_out = (const float*)d_in[12];
  float* out = (float*)d_out;

  // ws layout (bytes)
  char* ws = (char*)d_ws;
  unsigned short* vh_ws = (unsigned short*)ws;  // f16 [8][26588][32] = 13,613,056
  unsigned short* oa_ws =
      (unsigned short*)(ws + 13613056);  // bf16 [26588][384] = 20,419,584
  unsigned short* o_ws =
      (unsigned short*)(ws + 13613056 + 20419584);  // bf16 [26588][256]
  unsigned short* wt_val =
      (unsigned short*)(ws + 13613056 + 20419584 + 13613056);  // 131072 B
  unsigned short* wt_oa = wt_val + 256 * 256;                  // 196608 B
  unsigned short* wt_out = wt_oa + 384 * 256;                  // 131072 B

  prep_wt_kernel<<<896, 256, 0, stream>>>(W_val, W_off, W_attn, W_out, wt_val,
                                          wt_oa, wt_out);

  const int RB = (M_ROWS + 63) / 64;  // 416 row blocks
  // fused: vproj (strips 0-3) + offsets/attn (strips 4-9)
  gemm_fused01_kernel<<<dim3(RB, 10), 256, 0, stream>>>(
      value, query, wt_val, wt_oa, b_val, b_off, b_attn, mask, vh_ws, oa_ws,
      M_ROWS);

  dim3 g2((LQ + QPB - 1) / QPB, BS);
  gather_kernel<<<g2, 256, 0, stream>>>(refpts, (const __half*)vh_ws, oa_ws,
                                        o_ws);

  // out = o @ W_out + b_out -> f32
  gemm_out_kernel<<<dim3(RB, 4), 256, 0, stream>>>(o_ws, wt_out, b_out, out,
                                                   M_ROWS);
}

// Round 7
// 145.188 us; speedup vs baseline: 5.7332x; 1.0247x over previous
//
#include <hip/hip_runtime.h>
#include <hip/hip_bf16.h>
#include <hip/hip_fp16.h>
#include <stdint.h>

#define EMBED 256
#define HEADS 8
#define LEVELS 4
#define POINTS 4
#define HEAD_DIM 32
#define BS 2
#define LV_TOTAL 13294
#define LQ LV_TOTAL
#define TP 128 /* HEADS*LEVELS*POINTS */
#define M_ROWS (BS * LV_TOTAL) /* 26588 */
#define QPB 8

typedef __attribute__((ext_vector_type(8))) short bf16x8;
typedef __attribute__((ext_vector_type(4))) float f32x4;

static __device__ __forceinline__ unsigned short f2bf(float x) {
  __hip_bfloat16 h = __float2bfloat16(x);
  return *reinterpret_cast<unsigned short*>(&h);
}
static __device__ __forceinline__ float bf2f(unsigned short u) {
  return __uint_as_float(((unsigned int)u) << 16);
}
static __device__ __forceinline__ unsigned short f2hbits(float x) {
  __half h = __float2half(x);
  return *reinterpret_cast<unsigned short*>(&h);
}

// v_fma_mix_f32: acc(f32) += f16(sel vs of pk) * f16(sel ws of w)
#define MIX(acc, pk, w, vs, ws)                                          \
  asm("v_fma_mix_f32 %0, %1, %2, %0 op_sel:[" #vs "," #ws                \
      ",0] op_sel_hi:[1,1,0]"                                            \
      : "+v"(acc)                                                        \
      : "v"(pk), "v"(w))

// one bilinear corner: 8 dims (4 packed half2) scaled by f16 weight (half ws)
#define CORNER(cv, wreg, ws)                                             \
  MIX(acc[0], cv.x, wreg, 0, ws); MIX(acc[1], cv.x, wreg, 1, ws);        \
  MIX(acc[2], cv.y, wreg, 0, ws); MIX(acc[3], cv.y, wreg, 1, ws);        \
  MIX(acc[4], cv.z, wreg, 0, ws); MIX(acc[5], cv.z, wreg, 1, ws);        \
  MIX(acc[6], cv.w, wreg, 0, ws); MIX(acc[7], cv.w, wreg, 1, ws)

// issue the 4 corner loads + meta reads for sample `smp` into named regs
#define LOADS(i4v, wv, C0, C1, C2, C3, smp)                                   \
  {                                                                           \
    const int pos_ = (h * 16 + (smp)) ^ h;                                    \
    i4v = meta_idx[q][pos_];                                                  \
    wv = meta_w[q][pos_];                                                     \
    C0 = *(const uint4*)(vbase + (laneoff + ((unsigned int)i4v.x << 6)));     \
    C1 = *(const uint4*)(vbase + (laneoff + ((unsigned int)i4v.y << 6)));     \
    C2 = *(const uint4*)(vbase + (laneoff + ((unsigned int)i4v.z << 6)));     \
    C3 = *(const uint4*)(vbase + (laneoff + ((unsigned int)i4v.w << 6)));     \
  }

// ---------------------------------------------------------------------------
// prep_wt: transpose + convert all weight matrices to bf16 WT[n][k] layout.
// ---------------------------------------------------------------------------
__global__ __launch_bounds__(256) void prep_wt_kernel(
    const float* __restrict__ W_val, const float* __restrict__ W_off,
    const float* __restrict__ W_attn, const float* __restrict__ W_out,
    unsigned short* __restrict__ WT_val, unsigned short* __restrict__ WT_oa,
    unsigned short* __restrict__ WT_out) {
  const int bid = blockIdx.x;
  const int k = threadIdx.x;  // 0..255
  const float* src;
  unsigned short* dst;
  int n, N_src;
  if (bid < 256) {
    src = W_val; dst = WT_val; n = bid; N_src = 256;
  } else if (bid < 512) {
    src = W_off; dst = WT_oa; n = bid - 256; N_src = 256;
  } else if (bid < 640) {
    src = W_attn; dst = WT_oa + 256 * 256; n = bid - 512; N_src = 128;
  } else {
    src = W_out; dst = WT_out; n = bid - 640; N_src = 256;
  }
  dst[n * 256 + k] = f2bf(src[(size_t)k * N_src + n]);
}

// ---------------------------------------------------------------------------
// Shared GEMM body: C(M x NTOT) = A(M x 256) @ B(256 x NTOT) + bias, one
// 64-col strip per block, 128 rows per block. B panel (64x256 bf16, 32 KB)
// staged to LDS with XOR swizzle; 4 waves; each wave owns rows
// {base+wave*16, base+wave*16+64}; per kk: 2 A-frags, 4 ds_read_b128, 8 MFMA.
// OUT_MODE: 0=f32, 1=bf16, 2=f16 head-major vh[col>>5][row][col&31].
// ---------------------------------------------------------------------------
template <int NTOT, bool A_BF16, int OUT_MODE, bool MASKED, bool SPLIT_BIAS>
static __device__ __forceinline__ void gemm_body(
    unsigned short* bpanel, const void* __restrict__ Av,
    const unsigned short* __restrict__ BT, const float* __restrict__ bias0,
    const float* __restrict__ bias1, const uint8_t* __restrict__ mask,
    void* __restrict__ Cv, int M, int strip) {
  const int tid = threadIdx.x;
  const int col0 = strip * 64;

  // ---- stage B panel (64 cols x 256 k, bf16), XOR-swizzled ----
#pragma unroll
  for (int it = 0; it < 8; ++it) {
    int c = it * 256 + tid;  // chunk id 0..2047 (16B chunks)
    int col = c >> 5;        // 0..63
    int kc = c & 31;         // 16B chunk within the col's 512B row
    uint4 vdat = *(const uint4*)(BT + ((size_t)(col0 + col)) * 256 + kc * 8);
    int byteoff = (col << 9) + ((kc << 4) ^ ((col & 7) << 4));
    *(uint4*)((char*)bpanel + byteoff) = vdat;
  }
  __syncthreads();

  const int wave = tid >> 6;
  const int lane = tid & 63;
  const int lr = lane & 15;
  const int kq = lane >> 4;  // 0..3
  const int rowW = blockIdx.x * 128 + wave * 16;
  const int ar0 = min(rowW + lr, M - 1);
  const int ar1 = min(rowW + 64 + lr, M - 1);

  f32x4 acc[2][4];
#pragma unroll
  for (int ri = 0; ri < 2; ++ri)
#pragma unroll
    for (int c = 0; c < 4; ++c) acc[ri][c] = (f32x4){0.f, 0.f, 0.f, 0.f};

  const float* Af = (const float*)Av;
  const unsigned short* Ab = (const unsigned short*)Av;

#pragma unroll
  for (int kk = 0; kk < 8; ++kk) {
    const int k0 = kk * 32 + kq * 8;
    bf16x8 a0, a1;
    if constexpr (A_BF16) {
      a0 = *(const bf16x8*)(Ab + (size_t)ar0 * 256 + k0);
      a1 = *(const bf16x8*)(Ab + (size_t)ar1 * 256 + k0);
    } else {
      float4 p0 = *(const float4*)(Af + (size_t)ar0 * 256 + k0);
      float4 p1 = *(const float4*)(Af + (size_t)ar0 * 256 + k0 + 4);
      float4 p2 = *(const float4*)(Af + (size_t)ar1 * 256 + k0);
      float4 p3 = *(const float4*)(Af + (size_t)ar1 * 256 + k0 + 4);
      a0[0] = (short)f2bf(p0.x); a0[1] = (short)f2bf(p0.y);
      a0[2] = (short)f2bf(p0.z); a0[3] = (short)f2bf(p0.w);
      a0[4] = (short)f2bf(p1.x); a0[5] = (short)f2bf(p1.y);
      a0[6] = (short)f2bf(p1.z); a0[7] = (short)f2bf(p1.w);
      a1[0] = (short)f2bf(p2.x); a1[1] = (short)f2bf(p2.y);
      a1[2] = (short)f2bf(p2.z); a1[3] = (short)f2bf(p2.w);
      a1[4] = (short)f2bf(p3.x); a1[5] = (short)f2bf(p3.y);
      a1[6] = (short)f2bf(p3.z); a1[7] = (short)f2bf(p3.w);
    }
#pragma unroll
    for (int c = 0; c < 4; ++c) {
      const int col = c * 16 + lr;
      const int byteoff = (col << 9) + (((k0 * 2)) ^ ((col & 7) << 4));
      bf16x8 bfrag = *(const bf16x8*)((const char*)bpanel + byteoff);
      acc[0][c] =
          __builtin_amdgcn_mfma_f32_16x16x32_bf16(a0, bfrag, acc[0][c], 0, 0, 0);
      acc[1][c] =
          __builtin_amdgcn_mfma_f32_16x16x32_bf16(a1, bfrag, acc[1][c], 0, 0, 0);
    }
  }

  // epilogue: D col = lane&15, row = (lane>>4)*4 + i   [m89-verified]
#pragma unroll
  for (int c = 0; c < 4; ++c) {
    const int col = col0 + c * 16 + lr;
    float bv;
    if constexpr (SPLIT_BIAS)
      bv = (col < 256) ? bias0[col] : bias1[col - 256];
    else
      bv = bias0[col];
#pragma unroll
    for (int ri = 0; ri < 2; ++ri) {
#pragma unroll
      for (int i = 0; i < 4; ++i) {
        const int row = rowW + ri * 64 + kq * 4 + i;
        if (row < M) {
          float o = acc[ri][c][i] + bv;
          if constexpr (MASKED) {
            if (mask[row]) o = 0.f;
          }
          if constexpr (OUT_MODE == 0) {
            ((float*)Cv)[(size_t)row * NTOT + col] = o;
          } else if constexpr (OUT_MODE == 1) {
            ((unsigned short*)Cv)[(size_t)row * NTOT + col] = f2bf(o);
          } else {
            ((unsigned short*)Cv)[(size_t)(col >> 5) * ((size_t)M * 32) +
                                  (size_t)row * 32 + (col & 31)] = f2hbits(o);
          }
        }
      }
    }
  }
}

// fat kernel: strips 0-3 = vproj (value -> f16 head-major vh),
//             strips 4-9 = oa (query -> bf16 [off|attn])
__global__ __launch_bounds__(256) void gemm_fused01_kernel(
    const float* __restrict__ value, const float* __restrict__ query,
    const unsigned short* __restrict__ wt_val,
    const unsigned short* __restrict__ wt_oa, const float* __restrict__ b_val,
    const float* __restrict__ b_off, const float* __restrict__ b_attn,
    const uint8_t* __restrict__ mask, unsigned short* __restrict__ vh,
    unsigned short* __restrict__ oa, int M) {
  __shared__ uint4 bpanel4[2048];  // 32 KB
  unsigned short* bp = (unsigned short*)bpanel4;
  if (blockIdx.y < 4)
    gemm_body<256, false, 2, true, false>(bp, value, wt_val, b_val, nullptr,
                                          mask, vh, M, blockIdx.y);
  else
    gemm_body<384, false, 1, false, true>(bp, query, wt_oa, b_off, b_attn,
                                          nullptr, oa, M, blockIdx.y - 4);
}

__global__ __launch_bounds__(256) void gemm_out_kernel(
    const unsigned short* __restrict__ o_in,
    const unsigned short* __restrict__ wt_out, const float* __restrict__ b_out,
    float* __restrict__ out, int M) {
  __shared__ uint4 bpanel4[2048];
  unsigned short* bp = (unsigned short*)bpanel4;
  gemm_body<256, true, 0, false, false>(bp, o_in, wt_out, b_out, nullptr,
                                        nullptr, out, M, blockIdx.y);
}

// ---------------------------------------------------------------------------
// query remap: level-0 blocks (bid<1250) cover a 2-row x 4-col spatial patch
// of the 100x100 level-0 raster (bijective); later blocks stay linear.
// ---------------------------------------------------------------------------
static __device__ __forceinline__ int qmap_of(int bid, int r) {
  if (bid < 1250) {
    int ty = bid / 25, tx = bid - ty * 25;
    return (ty * 2 + (r >> 2)) * 100 + tx * 4 + (r & 3);
  }
  return bid * 8 + r;
}

// ---------------------------------------------------------------------------
// gather_kernel: per block QPB(8) queries of one batch, 256 threads.
// v is f16 head-major vh[h][b*LV+lv][32].  Gather inner loop: depth-2
// software pipeline (A/B corner buffers) of v_fma_mix_f32 consumers, so 4
// loads stay in flight across each consume (vmcnt(4) instead of vmcnt(0)).
// ---------------------------------------------------------------------------
__global__ __launch_bounds__(256) void gather_kernel(
    const float* __restrict__ refpts,
    const __half* __restrict__ vh,          // f16 head-major
    const unsigned short* __restrict__ oa,  // bf16 (BS*LQ, 384) [off|attn]
    unsigned short* __restrict__ o_out) {   // bf16 (BS*LQ, 256)
  __shared__ float attn_s[QPB][TP];      // 4 KB
  __shared__ float ref_s[QPB][LEVELS][2];
  __shared__ ushort4 meta_idx[QPB][TP];  // 8 KB
  __shared__ uint2 meta_w[QPB][TP];      // 8 KB (4x f16 bits)

  const int b = blockIdx.y;
  const int bid = blockIdx.x;
  const int tid = threadIdx.x;

  int qmap[QPB];
#pragma unroll
  for (int r = 0; r < QPB; ++r) qmap[r] = min(qmap_of(bid, r), LQ - 1);

  // ---- load offsets (col = tid, one per query, stays in registers) ----
  float accOff[QPB];
#pragma unroll
  for (int r = 0; r < QPB; ++r) {
    size_t row = (size_t)b * LQ + qmap[r];
    accOff[r] = bf2f(oa[row * 384 + tid]);
  }
  // ---- load attn logits to LDS ----
#pragma unroll
  for (int i = 0; i < 4; ++i) {
    int idx = i * 256 + tid;  // 0..1023
    int r = idx >> 7, col = idx & 127;
    size_t row = (size_t)b * LQ + qmap[r];
    attn_s[r][col] = bf2f(oa[row * 384 + 256 + col]);
  }
  // ---- reference points ----
  if (tid < QPB * LEVELS * 2) {
    int r = tid / (LEVELS * 2);
    int rem = tid % (LEVELS * 2);
    ref_s[r][rem / 2][rem % 2] =
        refpts[((size_t)b * LQ + qmap[r]) * (LEVELS * 2) + rem];
  }
  __syncthreads();

  // ---- softmax over 16 per (query, head) ----
  if (tid < QPB * HEADS) {
    int r = tid / HEADS, h = tid % HEADS;
    float* a = &attn_s[r][h * 16];
    float m = a[0];
#pragma unroll
    for (int i = 1; i < 16; ++i) m = fmaxf(m, a[i]);
    float e[16];
    float s = 0.f;
#pragma unroll
    for (int i = 0; i < 16; ++i) {
      e[i] = __expf(a[i] - m);
      s += e[i];
    }
    float inv = 1.f / s;
#pragma unroll
    for (int i = 0; i < 16; ++i) a[i] = e[i] * inv;
  }
  __syncthreads();

  // ---- meta precompute (clamped corner idx4 + premultiplied f16 weights) ----
  {
    float other[QPB];
#pragma unroll
    for (int r = 0; r < QPB; ++r) other[r] = __shfl_xor(accOff[r], 1, 64);

    const int s = tid >> 1;  // sample 0..127 == h*16 + l*4 + p
    const int isOdd = tid & 1;
    const int l = (s >> 2) & 3;
    const int W = (l == 0) ? 100 : (l == 1) ? 50 : (l == 2) ? 25 : 13;
    const int base = (l == 0) ? 0 : (l == 1) ? 10000 : (l == 2) ? 12500 : 13125;
    const float fW = (float)W;
    const int posx = s ^ ((s >> 4) & 7);  // bank swizzle, involution

#pragma unroll
    for (int rr = 0; rr < 4; ++rr) {
      int r = isOdd ? (4 + rr) : rr;
      float ox = isOdd ? other[r] : accOff[r];
      float oy = isOdd ? accOff[r] : other[r];
      float rx = ref_s[r][l][0];
      float ry = ref_s[r][l][1];
      float aw = attn_s[r][s];
      float x = fmaf(rx, fW, ox) - 0.5f;
      float y = fmaf(ry, fW, oy) - 0.5f;  // H == W for all levels
      float x0f = floorf(x), y0f = floorf(y);
      float lw = x - x0f, lh = y - y0f;
      int x0 = (int)x0f, y0 = (int)y0f;
      int x1 = x0 + 1, y1 = y0 + 1;
      bool x0v = (x0 >= 0) && (x0 < W);
      bool x1v = (x1 >= 0) && (x1 < W);
      bool y0v = (y0 >= 0) && (y0 < W);
      bool y1v = (y1 >= 0) && (y1 < W);
      int xc0 = min(max(x0, 0), W - 1), xc1 = min(max(x1, 0), W - 1);
      int yc0 = min(max(y0, 0), W - 1), yc1 = min(max(y1, 0), W - 1);
      float w00 = (1.f - lh) * (1.f - lw) * aw;
      float w01 = (1.f - lh) * lw * aw;
      float w10 = lh * (1.f - lw) * aw;
      float w11 = lh * lw * aw;
      unsigned int u00 = f2hbits((x0v && y0v) ? w00 : 0.f);
      unsigned int u01 = f2hbits((x1v && y0v) ? w01 : 0.f);
      unsigned int u10 = f2hbits((x0v && y1v) ? w10 : 0.f);
      unsigned int u11 = f2hbits((x1v && y1v) ? w11 : 0.f);
      meta_w[r][posx] = make_uint2(u00 | (u01 << 16), u10 | (u11 << 16));
      meta_idx[r][posx] = make_ushort4(
          (unsigned short)(yc0 * W + xc0 + base),
          (unsigned short)(yc0 * W + xc1 + base),
          (unsigned short)(yc1 * W + xc0 + base),
          (unsigned short)(yc1 * W + xc1 + base));
    }
  }
  __syncthreads();

  // ---- gather: thread = (q = wave*2 + lane>>5, h, t dim-octet) ----
  {
    const int lane = tid & 63;
    const int q = (tid >> 6) * 2 + (lane >> 5);  // 0..7
    const int h = (lane >> 2) & 7;               // head
    const int t = lane & 3;                      // dim octet (8 dims)
    // uniform base (SGPR) + 32-bit per-lane offset
    const char* vbase = (const char*)(vh + (size_t)b * LV_TOTAL * 32);
    const unsigned int laneoff =
        ((unsigned int)h * (M_ROWS * 32) + (unsigned int)t * 8) * 2u;

    float acc[8];
#pragma unroll
    for (int j = 0; j < 8; ++j) acc[j] = 0.f;

    // depth-2 pipeline: A/B buffers; issue next sample's loads before
    // consuming current (keeps 4 x 16B loads in flight -> vmcnt(4)).
    ushort4 iA, iB;
    uint2 wA, wB;
    uint4 A0, A1, A2, A3, B0, B1, B2, B3;
    LOADS(iA, wA, A0, A1, A2, A3, 0);
#pragma unroll
    for (int it = 0; it < 8; ++it) {
      LOADS(iB, wB, B0, B1, B2, B3, it * 2 + 1);
      CORNER(A0, wA.x, 0);
      CORNER(A1, wA.x, 1);
      CORNER(A2, wA.y, 0);
      CORNER(A3, wA.y, 1);
      if (it < 7) LOADS(iA, wA, A0, A1, A2, A3, it * 2 + 2);
      CORNER(B0, wB.x, 0);
      CORNER(B1, wB.x, 1);
      CORNER(B2, wB.y, 0);
      CORNER(B3, wB.y, 1);
    }

    const int qg = qmap[q];
    if (qmap_of(bid, q) < LQ) {
      uint4 pk;
      pk.x = (unsigned int)f2bf(acc[0]) | ((unsigned int)f2bf(acc[1]) << 16);
      pk.y = (unsigned int)f2bf(acc[2]) | ((unsigned int)f2bf(acc[3]) << 16);
      pk.z = (unsigned int)f2bf(acc[4]) | ((unsigned int)f2bf(acc[5]) << 16);
      pk.w = (unsigned int)f2bf(acc[6]) | ((unsigned int)f2bf(acc[7]) << 16);
      *(uint4*)(o_out + ((size_t)b * LQ + qg) * EMBED + h * HEAD_DIM + t * 8) =
          pk;
    }
  }
}

// ---------------------------------------------------------------------------
extern "C" void kernel_launch(void* const* d_in, const int* in_sizes, int n_in,
                              void* d_out, int out_size, void* d_ws,
                              size_t ws_size, hipStream_t stream) {
  const float* query = (const float*)d_in[0];
  const float* refpts = (const float*)d_in[1];
  const float* value = (const float*)d_in[2];
  const uint8_t* mask = (const uint8_t*)d_in[3];
  // d_in[4] = spatial_shapes (hardcoded: {100,100},{50,50},{25,25},{13,13})
  const float* W_off = (const float*)d_in[5];
  const float* b_off = (const float*)d_in[6];
  const float* W_attn = (const float*)d_in[7];
  const float* b_attn = (const float*)d_in[8];
  const float* W_val = (const float*)d_in[9];
  const float* b_val = (const float*)d_in[10];
  const float* W_out = (const float*)d_in[11];
  const float* b_out = (const float*)d_in[12];
  float* out = (float*)d_out;

  // ws layout (bytes)
  char* ws = (char*)d_ws;
  unsigned short* vh_ws = (unsigned short*)ws;  // f16 [8][26588][32] = 13,613,056
  unsigned short* oa_ws =
      (unsigned short*)(ws + 13613056);  // bf16 [26588][384] = 20,419,584
  unsigned short* o_ws =
      (unsigned short*)(ws + 13613056 + 20419584);  // bf16 [26588][256]
  unsigned short* wt_val =
      (unsigned short*)(ws + 13613056 + 20419584 + 13613056);  // 131072 B
  unsigned short* wt_oa = wt_val + 256 * 256;                  // 196608 B
  unsigned short* wt_out = wt_oa + 384 * 256;                  // 131072 B

  prep_wt_kernel<<<896, 256, 0, stream>>>(W_val, W_off, W_attn, W_out, wt_val,
                                          wt_oa, wt_out);

  const int RB = (M_ROWS + 127) / 128;  // 208 row blocks
  // fused: vproj (strips 0-3) + offsets/attn (strips 4-9)
  gemm_fused01_kernel<<<dim3(RB, 10), 256, 0, stream>>>(
      value, query, wt_val, wt_oa, b_val, b_off, b_attn, mask, vh_ws, oa_ws,
      M_ROWS);

  dim3 g2((LQ + QPB - 1) / QPB, BS);
  gather_kernel<<<g2, 256, 0, stream>>>(refpts, (const __half*)vh_ws, oa_ws,
                                        o_ws);

  // out = o @ W_out + b_out -> f32
  gemm_out_kernel<<<dim3(RB, 4), 256, 0, stream>>>(o_ws, wt_out, b_out, out,
                                                   M_ROWS);
}